// Round 10
// baseline (221.127 us; speedup 1.0000x reference)
//
#include <hip/hip_runtime.h>
#include <hip/hip_bf16.h>

// GraphSAGE 2-layer encoder, MI355X. Round 22.
// - A/B CONCLUDED (r19 vs r20 vs r21): 8-wave gemm12 costs ~5.5us, NBIN 391
//   costs ~2.8us. BOTH reverted -> gemm12 frozen at r19's 4-wave 256-thread
//   form (199.2us config, best measured).
// - NEW single lever: per-NODE direct binning eliminates k_csr entirely.
//   binprep scatters srcs[dst*64 + atomicAdd(&cursor[dst],1)] = src directly
//   (no LDS histogram, no reservation, no barriers). Gather kernels derive
//   beg = node*64, deg = cursor[node]. Removes: k_csr launch (2 passes over
//   staged, 1.6M LDS atomics), the staged buffer (12.8MB W + 25.6MB R), the
//   offs2 buffer, one launch gap. Cost: 800K scattered atomics on 200KB of
//   counters (~5us, deg~16 so contention trivial) + scattered 4B stores
//   (same line count as before - each node's run is 1-2 lines either way).
//   CAPN=64 >> max deg (~40 for Poisson(16) over 50K nodes); clamp included.
// 4 kernels + 200KB memset.

typedef short short8 __attribute__((ext_vector_type(8)));
typedef float floatx4 __attribute__((ext_vector_type(4)));

#define IN_C  128
#define HID_C 256
#define OUT_C 128
#define CAPN  64       // per-node slot capacity (deg ~ Poisson(16), max ~40)
#define CHUNK 3072     // edges per binning block
#define NBIN  261      // binning blocks: 261*3072 >= 800000
#define NCAST 200      // x-cast blocks
#define NWPK  56       // weight-pack blocks

static __device__ __forceinline__ unsigned short f2b(float f) {
  union { float f; unsigned u; } v; v.f = f;
  unsigned r = v.u + 0x7fffu + ((v.u >> 16) & 1u);   // RNE
  return (unsigned short)(r >> 16);
}
static __device__ __forceinline__ unsigned pack2(float a, float b) {
  return (unsigned)f2b(a) | ((unsigned)f2b(b) << 16);
}
static __device__ __forceinline__ float lo2f(unsigned u) {
  union { unsigned u; float f; } v; v.u = u << 16; return v.f;
}
static __device__ __forceinline__ float hi2f(unsigned u) {
  union { unsigned u; float f; } v; v.u = u & 0xffff0000u; return v.f;
}

// ---------------- binprep: per-node binning + x cast + weight pack ----------------
// srcs[node*CAPN + k] = k-th incoming source for node; cursor[node] = deg.
// Weight pack (MFMA-fragment order): packed uint index j decomposes as
//   u = j&3, lane = (j>>2)&63, kk = (j>>8)&7, g = j>>11
//   n = g*16 + (lane&15), kc = kk*4 + (lane>>4), pc = kc*4 + u
// wpk1 logical row n = [W1l row n | W1r row n]; wpk2 row n = [W2l ; W2r]

__global__ void __launch_bounds__(512)
k_binprep(const int* __restrict__ ei, int E,
          int* __restrict__ cursor, int* __restrict__ srcs,
          const float* __restrict__ x, unsigned* __restrict__ xb, int nPairsX,
          const float* __restrict__ W1l, const float* __restrict__ W1r,
          const float* __restrict__ W2l, const float* __restrict__ W2r,
          unsigned* __restrict__ wpk1, unsigned* __restrict__ wpk2) {
  int blk = blockIdx.x, tid = threadIdx.x;

  if (blk >= NBIN) {
    if (blk < NBIN + NCAST) {           // x -> bf16 pairs
      for (int i = (blk - NBIN) * 512 + tid; i < nPairsX; i += NCAST * 512) {
        float2 v = reinterpret_cast<const float2*>(x)[i];
        xb[i] = pack2(v.x, v.y);
      }
    } else {                            // weight packing (65536 pairs, fragment order)
      for (int i = (blk - NBIN - NCAST) * 512 + tid; i < 65536; i += NWPK * 512) {
        int j = i & 32767;
        int u = j & 3;
        int lane = (j >> 2) & 63;
        int kk = (j >> 8) & 7;
        int g = j >> 11;                 // 0..15
        int n = g * 16 + (lane & 15);
        int kc = kk * 4 + (lane >> 4);
        int pc = kc * 4 + u;             // pair col 0..127
        if (i < 32768) {                 // wpk1
          const float* s = (pc < 64) ? (W1l + (size_t)n * 128 + pc * 2)
                                     : (W1r + (size_t)n * 128 + (pc - 64) * 2);
          float2 v = *reinterpret_cast<const float2*>(s);
          wpk1[j] = pack2(v.x, v.y);
        } else {                         // wpk2
          const float* s = (n < 128) ? (W2l + (size_t)n * 256 + pc * 2)
                                     : (W2r + (size_t)(n - 128) * 256 + pc * 2);
          float2 v = *reinterpret_cast<const float2*>(s);
          wpk2[j] = pack2(v.x, v.y);
        }
      }
    }
    return;
  }

  // binning path: per-node direct scatter (no LDS, no barriers)
  int e0 = blk * CHUNK;
  int e1 = min(e0 + CHUNK, E);
  for (int e = e0 + tid; e < e1; e += 512) {
    int dst = ei[E + e];
    int src = ei[e];
    int pos = atomicAdd(&cursor[dst], 1);
    if (pos < CAPN) srcs[dst * CAPN + pos] = src;
  }
}

// ---------------- mean aggregation: wave per node, 4 rows per wave-load ----------------

static __device__ __forceinline__ void acc8(float* s, uint4 p) {
  s[0] += lo2f(p.x); s[1] += hi2f(p.x);
  s[2] += lo2f(p.y); s[3] += hi2f(p.y);
  s[4] += lo2f(p.z); s[5] += hi2f(p.z);
  s[6] += lo2f(p.w); s[7] += hi2f(p.w);
}

__global__ void k_agg_store(const uint4* __restrict__ Z4,
                            const int* __restrict__ cnt, const int* __restrict__ srcs,
                            uint4* __restrict__ out4, int N) {
  int node = blockIdx.x * 4 + (threadIdx.x >> 6);
  if (node >= N) return;
  int lane = threadIdx.x & 63;
  int g = lane >> 4, c = lane & 15;
  int d = cnt[node];
  int dd = d < CAPN ? d : CAPN;
  int beg = node * CAPN, end = beg + dd;
  float s[8] = {};
  int j = beg;
  for (; j + 16 <= end; j += 16) {
    uint4 p0 = Z4[(size_t)srcs[j +      g] * 16 + c];
    uint4 p1 = Z4[(size_t)srcs[j +  4 + g] * 16 + c];
    uint4 p2 = Z4[(size_t)srcs[j +  8 + g] * 16 + c];
    uint4 p3 = Z4[(size_t)srcs[j + 12 + g] * 16 + c];
    acc8(s, p0); acc8(s, p1); acc8(s, p2); acc8(s, p3);
  }
  for (; j + 4 <= end; j += 4) {
    uint4 p = Z4[(size_t)srcs[j + g] * 16 + c];
    acc8(s, p);
  }
  if (j + g < end) {
    uint4 p = Z4[(size_t)srcs[j + g] * 16 + c];
    acc8(s, p);
  }
#pragma unroll
  for (int i = 0; i < 8; ++i) {
    s[i] += __shfl_xor(s[i], 16);
    s[i] += __shfl_xor(s[i], 32);
  }
  if (g == 0) {
    float inv = 1.0f / (float)(d > 0 ? d : 1);
    uint4 o;
    o.x = pack2(s[0] * inv, s[1] * inv);
    o.y = pack2(s[2] * inv, s[3] * inv);
    o.z = pack2(s[4] * inv, s[5] * inv);
    o.w = pack2(s[6] * inv, s[7] * inv);
    out4[(size_t)node * 16 + c] = o;
  }
}

// out = baseb + mean-gather(z); writes d_out (f32) once, no RMW
__global__ void k_agg_addout(const uint4* __restrict__ Z4,
                             const int* __restrict__ cnt, const int* __restrict__ srcs,
                             const uint4* __restrict__ Bb4,
                             float* __restrict__ Out, int N) {
  int node = blockIdx.x * 4 + (threadIdx.x >> 6);
  if (node >= N) return;
  int lane = threadIdx.x & 63;
  int g = lane >> 4, c = lane & 15;
  int d = cnt[node];
  int dd = d < CAPN ? d : CAPN;
  int beg = node * CAPN, end = beg + dd;
  float s[8] = {};
  int j = beg;
  for (; j + 16 <= end; j += 16) {
    uint4 p0 = Z4[(size_t)srcs[j +      g] * 16 + c];
    uint4 p1 = Z4[(size_t)srcs[j +  4 + g] * 16 + c];
    uint4 p2 = Z4[(size_t)srcs[j +  8 + g] * 16 + c];
    uint4 p3 = Z4[(size_t)srcs[j + 12 + g] * 16 + c];
    acc8(s, p0); acc8(s, p1); acc8(s, p2); acc8(s, p3);
  }
  for (; j + 4 <= end; j += 4) {
    uint4 p = Z4[(size_t)srcs[j + g] * 16 + c];
    acc8(s, p);
  }
  if (j + g < end) {
    uint4 p = Z4[(size_t)srcs[j + g] * 16 + c];
    acc8(s, p);
  }
#pragma unroll
  for (int i = 0; i < 8; ++i) {
    s[i] += __shfl_xor(s[i], 16);
    s[i] += __shfl_xor(s[i], 32);
  }
  if (g == 0) {
    float inv = 1.0f / (float)(d > 0 ? d : 1);
    uint4 bp = Bb4[(size_t)node * 16 + c];
    float4 o0, o1;
    o0.x = lo2f(bp.x) + s[0] * inv; o0.y = hi2f(bp.x) + s[1] * inv;
    o0.z = lo2f(bp.y) + s[2] * inv; o0.w = hi2f(bp.y) + s[3] * inv;
    o1.x = lo2f(bp.z) + s[4] * inv; o1.y = hi2f(bp.z) + s[5] * inv;
    o1.z = lo2f(bp.w) + s[6] * inv; o1.w = hi2f(bp.w) + s[7] * inv;
    float* op = Out + (size_t)node * 128 + c * 8;
    *reinterpret_cast<float4*>(op) = o0;
    *reinterpret_cast<float4*>(op + 4) = o1;
  }
}

// ---------------- fused dual-layer GEMM (r19 form, frozen) ----------------
// Tile: rows mBase..mBase+63, all 256 cols. One 32KB LDS buffer At:
//   phase A: staged [agg1|xb] (XOR-swizzled), GEMM1 vs wpk1 -> acc
//   phase B: h = relu(acc+b1) written back into At (bf16, same swizzle)
//   phase C: acc re-zeroed, GEMM2 vs wpk2 -> zb (waves 0,1) / baseb (waves 2,3)
// A-swizzle: 16B chunk d of row r lives at pos p = (d&16)|((d^r)&15).
// B loads: fragment-order packed (k_binprep), contiguous 1KB per wave-load.

static __device__ __forceinline__ void stage_dual(
    const unsigned short* A1, const unsigned short* A2, int mBase,
    unsigned short* At /* LDS 64x256 */) {
  int t = threadIdx.x;
#pragma unroll
  for (int it = 0; it < 8; ++it) {
    int q = it * 256 + t;
    int r = q >> 5;
    int p = q & 31;
    int d = (p & 16) | ((p ^ r) & 15);
    const unsigned short* g = (d < 16)
        ? (A1 + (size_t)(mBase + r) * 128 + d * 8)
        : (A2 + (size_t)(mBase + r) * 128 + (d - 16) * 8);
    __builtin_amdgcn_global_load_lds(
        (const __attribute__((address_space(1))) unsigned*)g,
        (__attribute__((address_space(3))) unsigned*)&At[q * 8], 16, 0, 0);
  }
}

__global__ void __launch_bounds__(256, 3)
k_gemm12(const unsigned short* __restrict__ A1, const unsigned short* __restrict__ A2,
         const unsigned short* __restrict__ Wpk1, const float* __restrict__ b1,
         const unsigned short* __restrict__ Wpk2, const float* __restrict__ b2,
         unsigned short* __restrict__ Zb, unsigned short* __restrict__ Bb, int M) {
  __shared__ unsigned short At[64 * 256];
  int mBase = blockIdx.x * 64;
  stage_dual(A1, A2, mBase, At);
  int lane = threadIdx.x & 63, wave = threadIdx.x >> 6;
  int l15 = lane & 15, quad = lane >> 4;
  const short8* Wf1 = reinterpret_cast<const short8*>(Wpk1);
  const short8* Wf2 = reinterpret_cast<const short8*>(Wpk2);

  // ---- GEMM1: [agg|x] @ wpk1^T ----
  floatx4 acc[4][4] = {};
  __syncthreads();
#pragma unroll 2
  for (int kk = 0; kk < 8; ++kk) {
    short8 b[4];
#pragma unroll
    for (int t = 0; t < 4; ++t)
      b[t] = Wf1[((wave * 4 + t) * 8 + kk) * 64 + lane];
    int kc = kk * 4 + quad;
#pragma unroll
    for (int s = 0; s < 4; ++s) {
      int row = s * 16 + l15;
      int pos = (kc & 16) | ((kc ^ row) & 15);
      short8 a = *reinterpret_cast<const short8*>(&At[row * 256 + pos * 8]);
#pragma unroll
      for (int t = 0; t < 4; ++t)
        acc[s][t] = __builtin_amdgcn_mfma_f32_16x16x32_bf16(a, b[t], acc[s][t], 0, 0, 0);
    }
  }
  __syncthreads();   // all GEMM1 reads of At complete

  // ---- write h = relu(acc + b1) into At (bf16, A-layout swizzle); kill acc ----
#pragma unroll
  for (int t = 0; t < 4; ++t) {
    int n = wave * 64 + t * 16 + l15;
    float bv = b1[n];
    int d = n >> 3, nl = n & 7;
#pragma unroll
    for (int s = 0; s < 4; ++s) {
#pragma unroll
      for (int r = 0; r < 4; ++r) {
        int m = s * 16 + quad * 4 + r;
        int pos = (d & 16) | ((d ^ m) & 15);
        At[m * 256 + pos * 8 + nl] = f2b(fmaxf(acc[s][t][r] + bv, 0.f));
      }
    }
  }
  // re-zero the SAME accumulator (ends acc's GEMM1 live range)
#pragma unroll
  for (int s = 0; s < 4; ++s)
#pragma unroll
    for (int t = 0; t < 4; ++t)
      acc[s][t] = floatx4{0.f, 0.f, 0.f, 0.f};
  __syncthreads();   // h tile visible to all waves

  // ---- GEMM2: h @ wpk2^T (same acc registers) ----
#pragma unroll 2
  for (int kk = 0; kk < 8; ++kk) {
    short8 b[4];
#pragma unroll
    for (int t = 0; t < 4; ++t)
      b[t] = Wf2[((wave * 4 + t) * 8 + kk) * 64 + lane];
    int kc = kk * 4 + quad;
#pragma unroll
    for (int s = 0; s < 4; ++s) {
      int row = s * 16 + l15;
      int pos = (kc & 16) | ((kc ^ row) & 15);
      short8 a = *reinterpret_cast<const short8*>(&At[row * 256 + pos * 8]);
#pragma unroll
      for (int t = 0; t < 4; ++t)
        acc[s][t] = __builtin_amdgcn_mfma_f32_16x16x32_bf16(a, b[t], acc[s][t], 0, 0, 0);
    }
  }
  if (wave < 2) {        // z path, cols 0..127, bf16, no bias
#pragma unroll
    for (int t = 0; t < 4; ++t) {
      int n = wave * 64 + t * 16 + l15;
#pragma unroll
      for (int s = 0; s < 4; ++s)
#pragma unroll
        for (int r = 0; r < 4; ++r) {
          int m = mBase + s * 16 + quad * 4 + r;
          if (m < M) Zb[(size_t)m * 128 + n] = f2b(acc[s][t][r]);
        }
    }
  } else {               // base path, cols 0..127, bf16 + bias
#pragma unroll
    for (int t = 0; t < 4; ++t) {
      int n = (wave - 2) * 64 + t * 16 + l15;
      float bv = b2[n];
#pragma unroll
      for (int s = 0; s < 4; ++s)
#pragma unroll
        for (int r = 0; r < 4; ++r) {
          int m = mBase + s * 16 + quad * 4 + r;
          if (m < M) Bb[(size_t)m * 128 + n] = f2b(acc[s][t][r] + bv);
        }
    }
  }
}

// ---------------- launch ----------------

extern "C" void kernel_launch(void* const* d_in, const int* in_sizes, int n_in,
                              void* d_out, int out_size, void* d_ws, size_t ws_size,
                              hipStream_t stream) {
  const float* x   = (const float*)d_in[0];
  const int*   ei  = (const int*)d_in[1];
  const float* W1l = (const float*)d_in[2];
  const float* b1  = (const float*)d_in[3];
  const float* W1r = (const float*)d_in[4];
  const float* W2l = (const float*)d_in[5];
  const float* b2  = (const float*)d_in[6];
  const float* W2r = (const float*)d_in[7];
  float* out = (float*)d_out;

  int N = in_sizes[0] / IN_C;   // 50000
  int E = in_sizes[1] / 2;      // 800000

  char* p = (char*)d_ws;
  auto alloc = [&](size_t bytes) -> void* {
    void* r = (void*)p;
    p += (bytes + 255) & ~(size_t)255;
    return r;
  };
  int* cursor = (int*)alloc((size_t)N * 4);               // per-node degree
  int* srcs   = (int*)alloc((size_t)N * CAPN * 4);        // gapped per-node runs
  unsigned* xb   = (unsigned*)alloc((size_t)N * IN_C * 2);   // N x 64 uints
  unsigned* agg1 = (unsigned*)alloc((size_t)N * IN_C * 2);
  unsigned short* zb = (unsigned short*)alloc((size_t)N * OUT_C * 2);
  unsigned short* baseb = (unsigned short*)alloc((size_t)N * OUT_C * 2);
  unsigned* wpk1 = (unsigned*)alloc((size_t)HID_C * 256 * 2);  // 32768 uints
  unsigned* wpk2 = (unsigned*)alloc((size_t)256 * HID_C * 2);  // 32768 uints
  (void)alloc(64 * 512);   // tail pad for last-block over-reads

  // per-node cursor zero, fused binning+prep (no csr pass)
  hipMemsetAsync(cursor, 0, (size_t)N * 4, stream);
  k_binprep<<<NBIN + NCAST + NWPK, 512, 0, stream>>>(
      ei, E, cursor, srcs, x, xb, N * IN_C / 2,
      W1l, W1r, W2l, W2r, wpk1, wpk2);

  int mBlocks = (N + 63) / 64;

  // layer-1 gather, then fused dual GEMM (h never hits global)
  k_agg_store<<<(N + 3) / 4, 256, 0, stream>>>(
      (const uint4*)xb, cursor, srcs, (uint4*)agg1, N);
  k_gemm12<<<mBlocks, 256, 0, stream>>>(
      (const unsigned short*)agg1, (const unsigned short*)xb,
      (const unsigned short*)wpk1, b1,
      (const unsigned short*)wpk2, b2, zb, baseb, N);

  // out = baseb + mean-gather(z)
  k_agg_addout<<<(N + 3) / 4, 256, 0, stream>>>(
      (const uint4*)zb, cursor, srcs, (const uint4*)baseb, out, N);
}

// Round 11
// 198.259 us; speedup vs baseline: 1.1153x; 1.1153x over previous
//
#include <hip/hip_runtime.h>
#include <hip/hip_bf16.h>

// GraphSAGE 2-layer encoder, MI355X. Round 23 = round 19 (re-anchor at best).
// - REVERT round-22 per-node binning: 800K global atomic-with-return on 50K
//   counters (3125 lines -> ~256 serialized L2 RMWs/line) + scattered 4B
//   stores dirtying partial lines across 12.8MB (FETCH 16MB read-back, WRITE
//   61MB) pushed binprep to 57us. The bucket scheme does the same increments
//   in LDS and scatters into dense per-bucket runs: that design is correct.
// - This file is the verified 199.2us configuration:
//   * r15 fragment-order weight pack (gemm12 59.8 -> 50.5, A/B'd)
//   * r18 direct-scatter bucket binprep (LDS histogram -> global run reserve
//     -> staged[atomicAdd(&lcur[b],1)]) (~-5us by decomposition)
//   * r19 4-wave 256-thread gemm12 (beats 8-wave by ~5.5us, r21 A/B)
//   * two-phase csr, dedicated high-occupancy gather kernels (r16 lesson:
//     fuse latency-bound phases only into high-occupancy kernels)
// 5 kernels + 1.6KB memset.

typedef short short8 __attribute__((ext_vector_type(8)));
typedef float floatx4 __attribute__((ext_vector_type(4)));

#define IN_C  128
#define HID_C 256
#define OUT_C 128
#define NBMAX 400      // buckets of 128 nodes: ceil(50000/128)=391
#define CHUNK 3072     // edges per binning block
#define CAP   2560     // per-bucket slot capacity (mean 2048, sigma ~45)
#define NBIN  261      // binning blocks: 261*3072 >= 800000
#define NCAST 200      // x-cast blocks
#define NWPK  56       // weight-pack blocks

static __device__ __forceinline__ unsigned short f2b(float f) {
  union { float f; unsigned u; } v; v.f = f;
  unsigned r = v.u + 0x7fffu + ((v.u >> 16) & 1u);   // RNE
  return (unsigned short)(r >> 16);
}
static __device__ __forceinline__ unsigned pack2(float a, float b) {
  return (unsigned)f2b(a) | ((unsigned)f2b(b) << 16);
}
static __device__ __forceinline__ float lo2f(unsigned u) {
  union { unsigned u; float f; } v; v.u = u << 16; return v.f;
}
static __device__ __forceinline__ float hi2f(unsigned u) {
  union { unsigned u; float f; } v; v.u = u & 0xffff0000u; return v.f;
}

// ---------------- binprep: binning + x cast + weight pack (one launch) ----------------
// staged value = (src<<7) | (dst&127); bucket b's run: [b*CAP, b*CAP+cursor[b])
// Weight pack (MFMA-fragment order): packed uint index j decomposes as
//   u = j&3, lane = (j>>2)&63, kk = (j>>8)&7, g = j>>11
//   n = g*16 + (lane&15), kc = kk*4 + (lane>>4), pc = kc*4 + u
// wpk1 logical row n = [W1l row n | W1r row n]; wpk2 row n = [W2l ; W2r]

__global__ void __launch_bounds__(512)
k_binprep(const int* __restrict__ ei, int E, int nb,
          int* __restrict__ cursor, unsigned* __restrict__ staged,
          const float* __restrict__ x, unsigned* __restrict__ xb, int nPairsX,
          const float* __restrict__ W1l, const float* __restrict__ W1r,
          const float* __restrict__ W2l, const float* __restrict__ W2r,
          unsigned* __restrict__ wpk1, unsigned* __restrict__ wpk2) {
  __shared__ int lh[512];
  __shared__ int lcur[NBMAX];
  int blk = blockIdx.x, tid = threadIdx.x;

  if (blk >= NBIN) {
    if (blk < NBIN + NCAST) {           // x -> bf16 pairs
      for (int i = (blk - NBIN) * 512 + tid; i < nPairsX; i += NCAST * 512) {
        float2 v = reinterpret_cast<const float2*>(x)[i];
        xb[i] = pack2(v.x, v.y);
      }
    } else {                            // weight packing (65536 pairs, fragment order)
      for (int i = (blk - NBIN - NCAST) * 512 + tid; i < 65536; i += NWPK * 512) {
        int j = i & 32767;
        int u = j & 3;
        int lane = (j >> 2) & 63;
        int kk = (j >> 8) & 7;
        int g = j >> 11;                 // 0..15
        int n = g * 16 + (lane & 15);
        int kc = kk * 4 + (lane >> 4);
        int pc = kc * 4 + u;             // pair col 0..127
        if (i < 32768) {                 // wpk1
          const float* s = (pc < 64) ? (W1l + (size_t)n * 128 + pc * 2)
                                     : (W1r + (size_t)n * 128 + (pc - 64) * 2);
          float2 v = *reinterpret_cast<const float2*>(s);
          wpk1[j] = pack2(v.x, v.y);
        } else {                         // wpk2
          const float* s = (n < 128) ? (W2l + (size_t)n * 256 + pc * 2)
                                     : (W2r + (size_t)(n - 128) * 256 + pc * 2);
          float2 v = *reinterpret_cast<const float2*>(s);
          wpk2[j] = pack2(v.x, v.y);
        }
      }
    }
    return;
  }

  // binning path: histogram -> reserve global runs -> direct scatter
  int e0 = blk * CHUNK;
  int e1 = min(e0 + CHUNK, E);
  lh[tid] = 0;
  __syncthreads();
  for (int e = e0 + tid; e < e1; e += 512)
    atomicAdd(&lh[((unsigned)ei[E + e]) >> 7], 1);
  __syncthreads();
  if (tid < nb)
    lcur[tid] = tid * CAP + atomicAdd(&cursor[tid], lh[tid]);
  __syncthreads();
  for (int e = e0 + tid; e < e1; e += 512) {
    int dst = ei[E + e];
    int src = ei[e];
    int b = ((unsigned)dst) >> 7;
    int pos = atomicAdd(&lcur[b], 1);
    staged[pos] = ((unsigned)src << 7) | (unsigned)(dst & 127);
  }
}

// ---------------- finalize: per-node (beg,end) + srcs (gapped) ----------------

__global__ void k_csr(const unsigned* __restrict__ staged, const int* __restrict__ cursor,
                      int2* __restrict__ offs2, int* __restrict__ srcs, int N) {
  __shared__ int cnt[128];
  __shared__ int cur[128];
  int b = blockIdx.x;
  int tid = threadIdx.x;                  // 256
  int gbeg = b * CAP, gend = gbeg + cursor[b];
  if (tid < 128) cnt[tid] = 0;
  __syncthreads();
  for (int j = gbeg + tid; j < gend; j += 256)
    atomicAdd(&cnt[staged[j] & 127], 1);
  __syncthreads();
  if (tid < 64) {
    int v0 = cnt[tid * 2], v1 = cnt[tid * 2 + 1];
    int s = v0 + v1;
#pragma unroll
    for (int off = 1; off < 64; off <<= 1) {
      int t = __shfl_up(s, off, 64);
      if (tid >= off) s += t;
    }
    int exclp = s - (v0 + v1);
    int node = b * 128 + tid * 2;
    int beg0 = gbeg + exclp;
    int beg1 = beg0 + v0;
    cur[tid * 2]     = beg0;
    cur[tid * 2 + 1] = beg1;
    if (node < N)     offs2[node]     = make_int2(beg0, beg1);
    if (node + 1 < N) offs2[node + 1] = make_int2(beg1, beg1 + v1);
  }
  __syncthreads();
  for (int j = gbeg + tid; j < gend; j += 256) {
    unsigned v = staged[j];
    int pos = atomicAdd(&cur[v & 127], 1);
    srcs[pos] = (int)(v >> 7);
  }
}

// ---------------- mean aggregation: wave per node, 4 rows per wave-load ----------------

static __device__ __forceinline__ void acc8(float* s, uint4 p) {
  s[0] += lo2f(p.x); s[1] += hi2f(p.x);
  s[2] += lo2f(p.y); s[3] += hi2f(p.y);
  s[4] += lo2f(p.z); s[5] += hi2f(p.z);
  s[6] += lo2f(p.w); s[7] += hi2f(p.w);
}

__global__ void k_agg_store(const uint4* __restrict__ Z4,
                            const int2* __restrict__ offs2, const int* __restrict__ srcs,
                            uint4* __restrict__ out4, int N) {
  int node = blockIdx.x * 4 + (threadIdx.x >> 6);
  if (node >= N) return;
  int lane = threadIdx.x & 63;
  int g = lane >> 4, c = lane & 15;
  int2 be = offs2[node];
  int beg = be.x, end = be.y;
  float s[8] = {};
  int j = beg;
  for (; j + 16 <= end; j += 16) {
    uint4 p0 = Z4[(size_t)srcs[j +      g] * 16 + c];
    uint4 p1 = Z4[(size_t)srcs[j +  4 + g] * 16 + c];
    uint4 p2 = Z4[(size_t)srcs[j +  8 + g] * 16 + c];
    uint4 p3 = Z4[(size_t)srcs[j + 12 + g] * 16 + c];
    acc8(s, p0); acc8(s, p1); acc8(s, p2); acc8(s, p3);
  }
  for (; j + 4 <= end; j += 4) {
    uint4 p = Z4[(size_t)srcs[j + g] * 16 + c];
    acc8(s, p);
  }
  if (j + g < end) {
    uint4 p = Z4[(size_t)srcs[j + g] * 16 + c];
    acc8(s, p);
  }
#pragma unroll
  for (int i = 0; i < 8; ++i) {
    s[i] += __shfl_xor(s[i], 16);
    s[i] += __shfl_xor(s[i], 32);
  }
  if (g == 0) {
    int d = end - beg;
    float inv = 1.0f / (float)(d > 0 ? d : 1);
    uint4 o;
    o.x = pack2(s[0] * inv, s[1] * inv);
    o.y = pack2(s[2] * inv, s[3] * inv);
    o.z = pack2(s[4] * inv, s[5] * inv);
    o.w = pack2(s[6] * inv, s[7] * inv);
    out4[(size_t)node * 16 + c] = o;
  }
}

// out = baseb + mean-gather(z); writes d_out (f32) once, no RMW
__global__ void k_agg_addout(const uint4* __restrict__ Z4,
                             const int2* __restrict__ offs2, const int* __restrict__ srcs,
                             const uint4* __restrict__ Bb4,
                             float* __restrict__ Out, int N) {
  int node = blockIdx.x * 4 + (threadIdx.x >> 6);
  if (node >= N) return;
  int lane = threadIdx.x & 63;
  int g = lane >> 4, c = lane & 15;
  int2 be = offs2[node];
  int beg = be.x, end = be.y;
  float s[8] = {};
  int j = beg;
  for (; j + 16 <= end; j += 16) {
    uint4 p0 = Z4[(size_t)srcs[j +      g] * 16 + c];
    uint4 p1 = Z4[(size_t)srcs[j +  4 + g] * 16 + c];
    uint4 p2 = Z4[(size_t)srcs[j +  8 + g] * 16 + c];
    uint4 p3 = Z4[(size_t)srcs[j + 12 + g] * 16 + c];
    acc8(s, p0); acc8(s, p1); acc8(s, p2); acc8(s, p3);
  }
  for (; j + 4 <= end; j += 4) {
    uint4 p = Z4[(size_t)srcs[j + g] * 16 + c];
    acc8(s, p);
  }
  if (j + g < end) {
    uint4 p = Z4[(size_t)srcs[j + g] * 16 + c];
    acc8(s, p);
  }
#pragma unroll
  for (int i = 0; i < 8; ++i) {
    s[i] += __shfl_xor(s[i], 16);
    s[i] += __shfl_xor(s[i], 32);
  }
  if (g == 0) {
    int d = end - beg;
    float inv = 1.0f / (float)(d > 0 ? d : 1);
    uint4 bp = Bb4[(size_t)node * 16 + c];
    float4 o0, o1;
    o0.x = lo2f(bp.x) + s[0] * inv; o0.y = hi2f(bp.x) + s[1] * inv;
    o0.z = lo2f(bp.y) + s[2] * inv; o0.w = hi2f(bp.y) + s[3] * inv;
    o1.x = lo2f(bp.z) + s[4] * inv; o1.y = hi2f(bp.z) + s[5] * inv;
    o1.z = lo2f(bp.w) + s[6] * inv; o1.w = hi2f(bp.w) + s[7] * inv;
    float* op = Out + (size_t)node * 128 + c * 8;
    *reinterpret_cast<float4*>(op) = o0;
    *reinterpret_cast<float4*>(op + 4) = o1;
  }
}

// ---------------- fused dual-layer GEMM (single reused accumulator) ----------------
// Tile: rows mBase..mBase+63, all 256 cols. One 32KB LDS buffer At:
//   phase A: staged [agg1|xb] (XOR-swizzled), GEMM1 vs wpk1 -> acc
//   phase B: h = relu(acc+b1) written back into At (bf16, same swizzle)
//   phase C: acc re-zeroed, GEMM2 vs wpk2 -> zb (waves 0,1) / baseb (waves 2,3)
// A-swizzle: 16B chunk d of row r lives at pos p = (d&16)|((d^r)&15).
// B loads: fragment-order packed (k_binprep), contiguous 1KB per wave-load.

static __device__ __forceinline__ void stage_dual(
    const unsigned short* A1, const unsigned short* A2, int mBase,
    unsigned short* At /* LDS 64x256 */) {
  int t = threadIdx.x;
#pragma unroll
  for (int it = 0; it < 8; ++it) {
    int q = it * 256 + t;
    int r = q >> 5;
    int p = q & 31;
    int d = (p & 16) | ((p ^ r) & 15);
    const unsigned short* g = (d < 16)
        ? (A1 + (size_t)(mBase + r) * 128 + d * 8)
        : (A2 + (size_t)(mBase + r) * 128 + (d - 16) * 8);
    __builtin_amdgcn_global_load_lds(
        (const __attribute__((address_space(1))) unsigned*)g,
        (__attribute__((address_space(3))) unsigned*)&At[q * 8], 16, 0, 0);
  }
}

__global__ void __launch_bounds__(256, 3)
k_gemm12(const unsigned short* __restrict__ A1, const unsigned short* __restrict__ A2,
         const unsigned short* __restrict__ Wpk1, const float* __restrict__ b1,
         const unsigned short* __restrict__ Wpk2, const float* __restrict__ b2,
         unsigned short* __restrict__ Zb, unsigned short* __restrict__ Bb, int M) {
  __shared__ unsigned short At[64 * 256];
  int mBase = blockIdx.x * 64;
  stage_dual(A1, A2, mBase, At);
  int lane = threadIdx.x & 63, wave = threadIdx.x >> 6;
  int l15 = lane & 15, quad = lane >> 4;
  const short8* Wf1 = reinterpret_cast<const short8*>(Wpk1);
  const short8* Wf2 = reinterpret_cast<const short8*>(Wpk2);

  // ---- GEMM1: [agg|x] @ wpk1^T ----
  floatx4 acc[4][4] = {};
  __syncthreads();
#pragma unroll 2
  for (int kk = 0; kk < 8; ++kk) {
    short8 b[4];
#pragma unroll
    for (int t = 0; t < 4; ++t)
      b[t] = Wf1[((wave * 4 + t) * 8 + kk) * 64 + lane];
    int kc = kk * 4 + quad;
#pragma unroll
    for (int s = 0; s < 4; ++s) {
      int row = s * 16 + l15;
      int pos = (kc & 16) | ((kc ^ row) & 15);
      short8 a = *reinterpret_cast<const short8*>(&At[row * 256 + pos * 8]);
#pragma unroll
      for (int t = 0; t < 4; ++t)
        acc[s][t] = __builtin_amdgcn_mfma_f32_16x16x32_bf16(a, b[t], acc[s][t], 0, 0, 0);
    }
  }
  __syncthreads();   // all GEMM1 reads of At complete

  // ---- write h = relu(acc + b1) into At (bf16, A-layout swizzle); kill acc ----
#pragma unroll
  for (int t = 0; t < 4; ++t) {
    int n = wave * 64 + t * 16 + l15;
    float bv = b1[n];
    int d = n >> 3, nl = n & 7;
#pragma unroll
    for (int s = 0; s < 4; ++s) {
#pragma unroll
      for (int r = 0; r < 4; ++r) {
        int m = s * 16 + quad * 4 + r;
        int pos = (d & 16) | ((d ^ m) & 15);
        At[m * 256 + pos * 8 + nl] = f2b(fmaxf(acc[s][t][r] + bv, 0.f));
      }
    }
  }
  // re-zero the SAME accumulator (ends acc's GEMM1 live range)
#pragma unroll
  for (int s = 0; s < 4; ++s)
#pragma unroll
    for (int t = 0; t < 4; ++t)
      acc[s][t] = floatx4{0.f, 0.f, 0.f, 0.f};
  __syncthreads();   // h tile visible to all waves

  // ---- GEMM2: h @ wpk2^T (same acc registers) ----
#pragma unroll 2
  for (int kk = 0; kk < 8; ++kk) {
    short8 b[4];
#pragma unroll
    for (int t = 0; t < 4; ++t)
      b[t] = Wf2[((wave * 4 + t) * 8 + kk) * 64 + lane];
    int kc = kk * 4 + quad;
#pragma unroll
    for (int s = 0; s < 4; ++s) {
      int row = s * 16 + l15;
      int pos = (kc & 16) | ((kc ^ row) & 15);
      short8 a = *reinterpret_cast<const short8*>(&At[row * 256 + pos * 8]);
#pragma unroll
      for (int t = 0; t < 4; ++t)
        acc[s][t] = __builtin_amdgcn_mfma_f32_16x16x32_bf16(a, b[t], acc[s][t], 0, 0, 0);
    }
  }
  if (wave < 2) {        // z path, cols 0..127, bf16, no bias
#pragma unroll
    for (int t = 0; t < 4; ++t) {
      int n = wave * 64 + t * 16 + l15;
#pragma unroll
      for (int s = 0; s < 4; ++s)
#pragma unroll
        for (int r = 0; r < 4; ++r) {
          int m = mBase + s * 16 + quad * 4 + r;
          if (m < M) Zb[(size_t)m * 128 + n] = f2b(acc[s][t][r]);
        }
    }
  } else {               // base path, cols 0..127, bf16 + bias
#pragma unroll
    for (int t = 0; t < 4; ++t) {
      int n = (wave - 2) * 64 + t * 16 + l15;
      float bv = b2[n];
#pragma unroll
      for (int s = 0; s < 4; ++s)
#pragma unroll
        for (int r = 0; r < 4; ++r) {
          int m = mBase + s * 16 + quad * 4 + r;
          if (m < M) Bb[(size_t)m * 128 + n] = f2b(acc[s][t][r] + bv);
        }
    }
  }
}

// ---------------- launch ----------------

extern "C" void kernel_launch(void* const* d_in, const int* in_sizes, int n_in,
                              void* d_out, int out_size, void* d_ws, size_t ws_size,
                              hipStream_t stream) {
  const float* x   = (const float*)d_in[0];
  const int*   ei  = (const int*)d_in[1];
  const float* W1l = (const float*)d_in[2];
  const float* b1  = (const float*)d_in[3];
  const float* W1r = (const float*)d_in[4];
  const float* W2l = (const float*)d_in[5];
  const float* b2  = (const float*)d_in[6];
  const float* W2r = (const float*)d_in[7];
  float* out = (float*)d_out;

  int N = in_sizes[0] / IN_C;   // 50000
  int E = in_sizes[1] / 2;      // 800000
  int nb = (N + 127) >> 7;      // 391

  char* p = (char*)d_ws;
  auto alloc = [&](size_t bytes) -> void* {
    void* r = (void*)p;
    p += (bytes + 255) & ~(size_t)255;
    return r;
  };
  int* cursor  = (int*)alloc((size_t)(nb + 1) * 4);
  unsigned* staged = (unsigned*)alloc((size_t)nb * CAP * 4);
  int2* offs2 = (int2*)alloc((size_t)N * 8);
  int* srcs   = (int*)alloc((size_t)nb * CAP * 4);
  unsigned* xb   = (unsigned*)alloc((size_t)N * IN_C * 2);   // N x 64 uints
  unsigned* agg1 = (unsigned*)alloc((size_t)N * IN_C * 2);
  unsigned short* zb = (unsigned short*)alloc((size_t)N * OUT_C * 2);
  unsigned short* baseb = (unsigned short*)alloc((size_t)N * OUT_C * 2);
  unsigned* wpk1 = (unsigned*)alloc((size_t)HID_C * 256 * 2);  // 32768 uints
  unsigned* wpk2 = (unsigned*)alloc((size_t)256 * HID_C * 2);  // 32768 uints
  (void)alloc(64 * 512);   // tail pad for last-block over-reads

  // cursor zero (counts are CAP-relative), fused binning+prep, finalize
  hipMemsetAsync(cursor, 0, (size_t)(nb + 1) * 4, stream);
  k_binprep<<<NBIN + NCAST + NWPK, 512, 0, stream>>>(
      ei, E, nb, cursor, staged, x, xb, N * IN_C / 2,
      W1l, W1r, W2l, W2r, wpk1, wpk2);
  k_csr<<<nb, 256, 0, stream>>>(staged, cursor, offs2, srcs, N);

  int mBlocks = (N + 63) / 64;

  // layer-1 gather, then fused dual GEMM (h never hits global)
  k_agg_store<<<(N + 3) / 4, 256, 0, stream>>>(
      (const uint4*)xb, offs2, srcs, (uint4*)agg1, N);
  k_gemm12<<<mBlocks, 256, 0, stream>>>(
      (const unsigned short*)agg1, (const unsigned short*)xb,
      (const unsigned short*)wpk1, b1,
      (const unsigned short*)wpk2, b2, zb, baseb, N);

  // out = baseb + mean-gather(z)
  k_agg_addout<<<(N + 3) / 4, 256, 0, stream>>>(
      (const uint4*)zb, offs2, srcs, (const uint4*)baseb, out, N);
}

// Round 12
// 196.855 us; speedup vs baseline: 1.1233x; 1.0071x over previous
//
#include <hip/hip_runtime.h>
#include <hip/hip_bf16.h>

// GraphSAGE 2-layer encoder, MI355X. Round 24.
// - Anchor (r19/r23, 198.3us) reproduced. All components evidence-backed:
//   r15 fragment-order weights, r18 bucket binprep, r19 4-wave gemm12,
//   dedicated high-occupancy gather kernels.
// - SINGLE LEVER: k_csr 256 -> 512 threads. It runs 391 blocks ~ 1.5
//   blocks/CU = 6 waves/CU, the worst TLP in the pipeline, on latency-bound
//   work (2 strided passes of 4B loads + LDS atomics, ~8 serial iters/thread).
//   512 threads halves serial iters (8->4) and doubles waves/CU (6->12).
//   Scan section (tid<64, wave 0) and indexing unchanged.
// 5 kernels + 1.6KB memset.

typedef short short8 __attribute__((ext_vector_type(8)));
typedef float floatx4 __attribute__((ext_vector_type(4)));

#define IN_C  128
#define HID_C 256
#define OUT_C 128
#define NBMAX 400      // buckets of 128 nodes: ceil(50000/128)=391
#define CHUNK 3072     // edges per binning block
#define CAP   2560     // per-bucket slot capacity (mean 2048, sigma ~45)
#define NBIN  261      // binning blocks: 261*3072 >= 800000
#define NCAST 200      // x-cast blocks
#define NWPK  56       // weight-pack blocks

static __device__ __forceinline__ unsigned short f2b(float f) {
  union { float f; unsigned u; } v; v.f = f;
  unsigned r = v.u + 0x7fffu + ((v.u >> 16) & 1u);   // RNE
  return (unsigned short)(r >> 16);
}
static __device__ __forceinline__ unsigned pack2(float a, float b) {
  return (unsigned)f2b(a) | ((unsigned)f2b(b) << 16);
}
static __device__ __forceinline__ float lo2f(unsigned u) {
  union { unsigned u; float f; } v; v.u = u << 16; return v.f;
}
static __device__ __forceinline__ float hi2f(unsigned u) {
  union { unsigned u; float f; } v; v.u = u & 0xffff0000u; return v.f;
}

// ---------------- binprep: binning + x cast + weight pack (one launch) ----------------
// staged value = (src<<7) | (dst&127); bucket b's run: [b*CAP, b*CAP+cursor[b])
// Weight pack (MFMA-fragment order): packed uint index j decomposes as
//   u = j&3, lane = (j>>2)&63, kk = (j>>8)&7, g = j>>11
//   n = g*16 + (lane&15), kc = kk*4 + (lane>>4), pc = kc*4 + u
// wpk1 logical row n = [W1l row n | W1r row n]; wpk2 row n = [W2l ; W2r]

__global__ void __launch_bounds__(512)
k_binprep(const int* __restrict__ ei, int E, int nb,
          int* __restrict__ cursor, unsigned* __restrict__ staged,
          const float* __restrict__ x, unsigned* __restrict__ xb, int nPairsX,
          const float* __restrict__ W1l, const float* __restrict__ W1r,
          const float* __restrict__ W2l, const float* __restrict__ W2r,
          unsigned* __restrict__ wpk1, unsigned* __restrict__ wpk2) {
  __shared__ int lh[512];
  __shared__ int lcur[NBMAX];
  int blk = blockIdx.x, tid = threadIdx.x;

  if (blk >= NBIN) {
    if (blk < NBIN + NCAST) {           // x -> bf16 pairs
      for (int i = (blk - NBIN) * 512 + tid; i < nPairsX; i += NCAST * 512) {
        float2 v = reinterpret_cast<const float2*>(x)[i];
        xb[i] = pack2(v.x, v.y);
      }
    } else {                            // weight packing (65536 pairs, fragment order)
      for (int i = (blk - NBIN - NCAST) * 512 + tid; i < 65536; i += NWPK * 512) {
        int j = i & 32767;
        int u = j & 3;
        int lane = (j >> 2) & 63;
        int kk = (j >> 8) & 7;
        int g = j >> 11;                 // 0..15
        int n = g * 16 + (lane & 15);
        int kc = kk * 4 + (lane >> 4);
        int pc = kc * 4 + u;             // pair col 0..127
        if (i < 32768) {                 // wpk1
          const float* s = (pc < 64) ? (W1l + (size_t)n * 128 + pc * 2)
                                     : (W1r + (size_t)n * 128 + (pc - 64) * 2);
          float2 v = *reinterpret_cast<const float2*>(s);
          wpk1[j] = pack2(v.x, v.y);
        } else {                         // wpk2
          const float* s = (n < 128) ? (W2l + (size_t)n * 256 + pc * 2)
                                     : (W2r + (size_t)(n - 128) * 256 + pc * 2);
          float2 v = *reinterpret_cast<const float2*>(s);
          wpk2[j] = pack2(v.x, v.y);
        }
      }
    }
    return;
  }

  // binning path: histogram -> reserve global runs -> direct scatter
  int e0 = blk * CHUNK;
  int e1 = min(e0 + CHUNK, E);
  lh[tid] = 0;
  __syncthreads();
  for (int e = e0 + tid; e < e1; e += 512)
    atomicAdd(&lh[((unsigned)ei[E + e]) >> 7], 1);
  __syncthreads();
  if (tid < nb)
    lcur[tid] = tid * CAP + atomicAdd(&cursor[tid], lh[tid]);
  __syncthreads();
  for (int e = e0 + tid; e < e1; e += 512) {
    int dst = ei[E + e];
    int src = ei[e];
    int b = ((unsigned)dst) >> 7;
    int pos = atomicAdd(&lcur[b], 1);
    staged[pos] = ((unsigned)src << 7) | (unsigned)(dst & 127);
  }
}

// ---------------- finalize: per-node (beg,end) + srcs (gapped) ----------------

__global__ void __launch_bounds__(512)
k_csr(const unsigned* __restrict__ staged, const int* __restrict__ cursor,
      int2* __restrict__ offs2, int* __restrict__ srcs, int N) {
  __shared__ int cnt[128];
  __shared__ int cur[128];
  int b = blockIdx.x;
  int tid = threadIdx.x;                  // 512
  int gbeg = b * CAP, gend = gbeg + cursor[b];
  if (tid < 128) cnt[tid] = 0;
  __syncthreads();
  for (int j = gbeg + tid; j < gend; j += 512)
    atomicAdd(&cnt[staged[j] & 127], 1);
  __syncthreads();
  if (tid < 64) {
    int v0 = cnt[tid * 2], v1 = cnt[tid * 2 + 1];
    int s = v0 + v1;
#pragma unroll
    for (int off = 1; off < 64; off <<= 1) {
      int t = __shfl_up(s, off, 64);
      if (tid >= off) s += t;
    }
    int exclp = s - (v0 + v1);
    int node = b * 128 + tid * 2;
    int beg0 = gbeg + exclp;
    int beg1 = beg0 + v0;
    cur[tid * 2]     = beg0;
    cur[tid * 2 + 1] = beg1;
    if (node < N)     offs2[node]     = make_int2(beg0, beg1);
    if (node + 1 < N) offs2[node + 1] = make_int2(beg1, beg1 + v1);
  }
  __syncthreads();
  for (int j = gbeg + tid; j < gend; j += 512) {
    unsigned v = staged[j];
    int pos = atomicAdd(&cur[v & 127], 1);
    srcs[pos] = (int)(v >> 7);
  }
}

// ---------------- mean aggregation: wave per node, 4 rows per wave-load ----------------

static __device__ __forceinline__ void acc8(float* s, uint4 p) {
  s[0] += lo2f(p.x); s[1] += hi2f(p.x);
  s[2] += lo2f(p.y); s[3] += hi2f(p.y);
  s[4] += lo2f(p.z); s[5] += hi2f(p.z);
  s[6] += lo2f(p.w); s[7] += hi2f(p.w);
}

__global__ void k_agg_store(const uint4* __restrict__ Z4,
                            const int2* __restrict__ offs2, const int* __restrict__ srcs,
                            uint4* __restrict__ out4, int N) {
  int node = blockIdx.x * 4 + (threadIdx.x >> 6);
  if (node >= N) return;
  int lane = threadIdx.x & 63;
  int g = lane >> 4, c = lane & 15;
  int2 be = offs2[node];
  int beg = be.x, end = be.y;
  float s[8] = {};
  int j = beg;
  for (; j + 16 <= end; j += 16) {
    uint4 p0 = Z4[(size_t)srcs[j +      g] * 16 + c];
    uint4 p1 = Z4[(size_t)srcs[j +  4 + g] * 16 + c];
    uint4 p2 = Z4[(size_t)srcs[j +  8 + g] * 16 + c];
    uint4 p3 = Z4[(size_t)srcs[j + 12 + g] * 16 + c];
    acc8(s, p0); acc8(s, p1); acc8(s, p2); acc8(s, p3);
  }
  for (; j + 4 <= end; j += 4) {
    uint4 p = Z4[(size_t)srcs[j + g] * 16 + c];
    acc8(s, p);
  }
  if (j + g < end) {
    uint4 p = Z4[(size_t)srcs[j + g] * 16 + c];
    acc8(s, p);
  }
#pragma unroll
  for (int i = 0; i < 8; ++i) {
    s[i] += __shfl_xor(s[i], 16);
    s[i] += __shfl_xor(s[i], 32);
  }
  if (g == 0) {
    int d = end - beg;
    float inv = 1.0f / (float)(d > 0 ? d : 1);
    uint4 o;
    o.x = pack2(s[0] * inv, s[1] * inv);
    o.y = pack2(s[2] * inv, s[3] * inv);
    o.z = pack2(s[4] * inv, s[5] * inv);
    o.w = pack2(s[6] * inv, s[7] * inv);
    out4[(size_t)node * 16 + c] = o;
  }
}

// out = baseb + mean-gather(z); writes d_out (f32) once, no RMW
__global__ void k_agg_addout(const uint4* __restrict__ Z4,
                             const int2* __restrict__ offs2, const int* __restrict__ srcs,
                             const uint4* __restrict__ Bb4,
                             float* __restrict__ Out, int N) {
  int node = blockIdx.x * 4 + (threadIdx.x >> 6);
  if (node >= N) return;
  int lane = threadIdx.x & 63;
  int g = lane >> 4, c = lane & 15;
  int2 be = offs2[node];
  int beg = be.x, end = be.y;
  float s[8] = {};
  int j = beg;
  for (; j + 16 <= end; j += 16) {
    uint4 p0 = Z4[(size_t)srcs[j +      g] * 16 + c];
    uint4 p1 = Z4[(size_t)srcs[j +  4 + g] * 16 + c];
    uint4 p2 = Z4[(size_t)srcs[j +  8 + g] * 16 + c];
    uint4 p3 = Z4[(size_t)srcs[j + 12 + g] * 16 + c];
    acc8(s, p0); acc8(s, p1); acc8(s, p2); acc8(s, p3);
  }
  for (; j + 4 <= end; j += 4) {
    uint4 p = Z4[(size_t)srcs[j + g] * 16 + c];
    acc8(s, p);
  }
  if (j + g < end) {
    uint4 p = Z4[(size_t)srcs[j + g] * 16 + c];
    acc8(s, p);
  }
#pragma unroll
  for (int i = 0; i < 8; ++i) {
    s[i] += __shfl_xor(s[i], 16);
    s[i] += __shfl_xor(s[i], 32);
  }
  if (g == 0) {
    int d = end - beg;
    float inv = 1.0f / (float)(d > 0 ? d : 1);
    uint4 bp = Bb4[(size_t)node * 16 + c];
    float4 o0, o1;
    o0.x = lo2f(bp.x) + s[0] * inv; o0.y = hi2f(bp.x) + s[1] * inv;
    o0.z = lo2f(bp.y) + s[2] * inv; o0.w = hi2f(bp.y) + s[3] * inv;
    o1.x = lo2f(bp.z) + s[4] * inv; o1.y = hi2f(bp.z) + s[5] * inv;
    o1.z = lo2f(bp.w) + s[6] * inv; o1.w = hi2f(bp.w) + s[7] * inv;
    float* op = Out + (size_t)node * 128 + c * 8;
    *reinterpret_cast<float4*>(op) = o0;
    *reinterpret_cast<float4*>(op + 4) = o1;
  }
}

// ---------------- fused dual-layer GEMM (single reused accumulator) ----------------
// Tile: rows mBase..mBase+63, all 256 cols. One 32KB LDS buffer At:
//   phase A: staged [agg1|xb] (XOR-swizzled), GEMM1 vs wpk1 -> acc
//   phase B: h = relu(acc+b1) written back into At (bf16, same swizzle)
//   phase C: acc re-zeroed, GEMM2 vs wpk2 -> zb (waves 0,1) / baseb (waves 2,3)
// A-swizzle: 16B chunk d of row r lives at pos p = (d&16)|((d^r)&15).
// B loads: fragment-order packed (k_binprep), contiguous 1KB per wave-load.

static __device__ __forceinline__ void stage_dual(
    const unsigned short* A1, const unsigned short* A2, int mBase,
    unsigned short* At /* LDS 64x256 */) {
  int t = threadIdx.x;
#pragma unroll
  for (int it = 0; it < 8; ++it) {
    int q = it * 256 + t;
    int r = q >> 5;
    int p = q & 31;
    int d = (p & 16) | ((p ^ r) & 15);
    const unsigned short* g = (d < 16)
        ? (A1 + (size_t)(mBase + r) * 128 + d * 8)
        : (A2 + (size_t)(mBase + r) * 128 + (d - 16) * 8);
    __builtin_amdgcn_global_load_lds(
        (const __attribute__((address_space(1))) unsigned*)g,
        (__attribute__((address_space(3))) unsigned*)&At[q * 8], 16, 0, 0);
  }
}

__global__ void __launch_bounds__(256, 3)
k_gemm12(const unsigned short* __restrict__ A1, const unsigned short* __restrict__ A2,
         const unsigned short* __restrict__ Wpk1, const float* __restrict__ b1,
         const unsigned short* __restrict__ Wpk2, const float* __restrict__ b2,
         unsigned short* __restrict__ Zb, unsigned short* __restrict__ Bb, int M) {
  __shared__ unsigned short At[64 * 256];
  int mBase = blockIdx.x * 64;
  stage_dual(A1, A2, mBase, At);
  int lane = threadIdx.x & 63, wave = threadIdx.x >> 6;
  int l15 = lane & 15, quad = lane >> 4;
  const short8* Wf1 = reinterpret_cast<const short8*>(Wpk1);
  const short8* Wf2 = reinterpret_cast<const short8*>(Wpk2);

  // ---- GEMM1: [agg|x] @ wpk1^T ----
  floatx4 acc[4][4] = {};
  __syncthreads();
#pragma unroll 2
  for (int kk = 0; kk < 8; ++kk) {
    short8 b[4];
#pragma unroll
    for (int t = 0; t < 4; ++t)
      b[t] = Wf1[((wave * 4 + t) * 8 + kk) * 64 + lane];
    int kc = kk * 4 + quad;
#pragma unroll
    for (int s = 0; s < 4; ++s) {
      int row = s * 16 + l15;
      int pos = (kc & 16) | ((kc ^ row) & 15);
      short8 a = *reinterpret_cast<const short8*>(&At[row * 256 + pos * 8]);
#pragma unroll
      for (int t = 0; t < 4; ++t)
        acc[s][t] = __builtin_amdgcn_mfma_f32_16x16x32_bf16(a, b[t], acc[s][t], 0, 0, 0);
    }
  }
  __syncthreads();   // all GEMM1 reads of At complete

  // ---- write h = relu(acc + b1) into At (bf16, A-layout swizzle); kill acc ----
#pragma unroll
  for (int t = 0; t < 4; ++t) {
    int n = wave * 64 + t * 16 + l15;
    float bv = b1[n];
    int d = n >> 3, nl = n & 7;
#pragma unroll
    for (int s = 0; s < 4; ++s) {
#pragma unroll
      for (int r = 0; r < 4; ++r) {
        int m = s * 16 + quad * 4 + r;
        int pos = (d & 16) | ((d ^ m) & 15);
        At[m * 256 + pos * 8 + nl] = f2b(fmaxf(acc[s][t][r] + bv, 0.f));
      }
    }
  }
  // re-zero the SAME accumulator (ends acc's GEMM1 live range)
#pragma unroll
  for (int s = 0; s < 4; ++s)
#pragma unroll
    for (int t = 0; t < 4; ++t)
      acc[s][t] = floatx4{0.f, 0.f, 0.f, 0.f};
  __syncthreads();   // h tile visible to all waves

  // ---- GEMM2: h @ wpk2^T (same acc registers) ----
#pragma unroll 2
  for (int kk = 0; kk < 8; ++kk) {
    short8 b[4];
#pragma unroll
    for (int t = 0; t < 4; ++t)
      b[t] = Wf2[((wave * 4 + t) * 8 + kk) * 64 + lane];
    int kc = kk * 4 + quad;
#pragma unroll
    for (int s = 0; s < 4; ++s) {
      int row = s * 16 + l15;
      int pos = (kc & 16) | ((kc ^ row) & 15);
      short8 a = *reinterpret_cast<const short8*>(&At[row * 256 + pos * 8]);
#pragma unroll
      for (int t = 0; t < 4; ++t)
        acc[s][t] = __builtin_amdgcn_mfma_f32_16x16x32_bf16(a, b[t], acc[s][t], 0, 0, 0);
    }
  }
  if (wave < 2) {        // z path, cols 0..127, bf16, no bias
#pragma unroll
    for (int t = 0; t < 4; ++t) {
      int n = wave * 64 + t * 16 + l15;
#pragma unroll
      for (int s = 0; s < 4; ++s)
#pragma unroll
        for (int r = 0; r < 4; ++r) {
          int m = mBase + s * 16 + quad * 4 + r;
          if (m < M) Zb[(size_t)m * 128 + n] = f2b(acc[s][t][r]);
        }
    }
  } else {               // base path, cols 0..127, bf16 + bias
#pragma unroll
    for (int t = 0; t < 4; ++t) {
      int n = (wave - 2) * 64 + t * 16 + l15;
      float bv = b2[n];
#pragma unroll
      for (int s = 0; s < 4; ++s)
#pragma unroll
        for (int r = 0; r < 4; ++r) {
          int m = mBase + s * 16 + quad * 4 + r;
          if (m < M) Bb[(size_t)m * 128 + n] = f2b(acc[s][t][r] + bv);
        }
    }
  }
}

// ---------------- launch ----------------

extern "C" void kernel_launch(void* const* d_in, const int* in_sizes, int n_in,
                              void* d_out, int out_size, void* d_ws, size_t ws_size,
                              hipStream_t stream) {
  const float* x   = (const float*)d_in[0];
  const int*   ei  = (const int*)d_in[1];
  const float* W1l = (const float*)d_in[2];
  const float* b1  = (const float*)d_in[3];
  const float* W1r = (const float*)d_in[4];
  const float* W2l = (const float*)d_in[5];
  const float* b2  = (const float*)d_in[6];
  const float* W2r = (const float*)d_in[7];
  float* out = (float*)d_out;

  int N = in_sizes[0] / IN_C;   // 50000
  int E = in_sizes[1] / 2;      // 800000
  int nb = (N + 127) >> 7;      // 391

  char* p = (char*)d_ws;
  auto alloc = [&](size_t bytes) -> void* {
    void* r = (void*)p;
    p += (bytes + 255) & ~(size_t)255;
    return r;
  };
  int* cursor  = (int*)alloc((size_t)(nb + 1) * 4);
  unsigned* staged = (unsigned*)alloc((size_t)nb * CAP * 4);
  int2* offs2 = (int2*)alloc((size_t)N * 8);
  int* srcs   = (int*)alloc((size_t)nb * CAP * 4);
  unsigned* xb   = (unsigned*)alloc((size_t)N * IN_C * 2);   // N x 64 uints
  unsigned* agg1 = (unsigned*)alloc((size_t)N * IN_C * 2);
  unsigned short* zb = (unsigned short*)alloc((size_t)N * OUT_C * 2);
  unsigned short* baseb = (unsigned short*)alloc((size_t)N * OUT_C * 2);
  unsigned* wpk1 = (unsigned*)alloc((size_t)HID_C * 256 * 2);  // 32768 uints
  unsigned* wpk2 = (unsigned*)alloc((size_t)256 * HID_C * 2);  // 32768 uints
  (void)alloc(64 * 512);   // tail pad for last-block over-reads

  // cursor zero (counts are CAP-relative), fused binning+prep, finalize
  hipMemsetAsync(cursor, 0, (size_t)(nb + 1) * 4, stream);
  k_binprep<<<NBIN + NCAST + NWPK, 512, 0, stream>>>(
      ei, E, nb, cursor, staged, x, xb, N * IN_C / 2,
      W1l, W1r, W2l, W2r, wpk1, wpk2);
  k_csr<<<nb, 512, 0, stream>>>(staged, cursor, offs2, srcs, N);

  int mBlocks = (N + 63) / 64;

  // layer-1 gather, then fused dual GEMM (h never hits global)
  k_agg_store<<<(N + 3) / 4, 256, 0, stream>>>(
      (const uint4*)xb, offs2, srcs, (uint4*)agg1, N);
  k_gemm12<<<mBlocks, 256, 0, stream>>>(
      (const unsigned short*)agg1, (const unsigned short*)xb,
      (const unsigned short*)wpk1, b1,
      (const unsigned short*)wpk2, b2, zb, baseb, N);

  // out = baseb + mean-gather(z)
  k_agg_addout<<<(N + 3) / 4, 256, 0, stream>>>(
      (const uint4*)zb, offs2, srcs, (const uint4*)baseb, out, N);
}

// Round 14
// 194.541 us; speedup vs baseline: 1.1367x; 1.0119x over previous
//
#include <hip/hip_runtime.h>
#include <hip/hip_bf16.h>

// GraphSAGE 2-layer encoder, MI355X. Round 26.
// - r25 FAILED correctness (absmax 0.378): the gather tail executed __shfl
//   INSIDE a divergent guard. CDNA ds_bpermute (pull) returns 0 when the
//   SOURCE lane is inactive; the source lane (off+g) has a different group
//   than the reader, so for deg>=16 with deg%4!=0 it was masked off ->
//   index 0 -> node accumulated Z row 0. FIX: hoist the __shfl out of the
//   guard (control flow is wave-uniform there); only the accumulate is
//   predicated. The 16- and 4-batch loops are non-divergent (uniform trip
//   counts) and were already correct.
// - Everything else identical to r25 / r24 anchor: r15 fragment-order
//   weights, r18 bucket binprep, r19 4-wave gemm12, r24 csr@512.
// 5 kernels + 1.6KB memset.

typedef short short8 __attribute__((ext_vector_type(8)));
typedef float floatx4 __attribute__((ext_vector_type(4)));

#define IN_C  128
#define HID_C 256
#define OUT_C 128
#define NBMAX 400      // buckets of 128 nodes: ceil(50000/128)=391
#define CHUNK 3072     // edges per binning block
#define CAP   2560     // per-bucket slot capacity (mean 2048, sigma ~45)
#define NBIN  261      // binning blocks: 261*3072 >= 800000
#define NCAST 200      // x-cast blocks
#define NWPK  56       // weight-pack blocks

static __device__ __forceinline__ unsigned short f2b(float f) {
  union { float f; unsigned u; } v; v.f = f;
  unsigned r = v.u + 0x7fffu + ((v.u >> 16) & 1u);   // RNE
  return (unsigned short)(r >> 16);
}
static __device__ __forceinline__ unsigned pack2(float a, float b) {
  return (unsigned)f2b(a) | ((unsigned)f2b(b) << 16);
}
static __device__ __forceinline__ float lo2f(unsigned u) {
  union { unsigned u; float f; } v; v.u = u << 16; return v.f;
}
static __device__ __forceinline__ float hi2f(unsigned u) {
  union { unsigned u; float f; } v; v.u = u & 0xffff0000u; return v.f;
}

// ---------------- binprep: binning + x cast + weight pack (one launch) ----------------
// staged value = (src<<7) | (dst&127); bucket b's run: [b*CAP, b*CAP+cursor[b])
// Weight pack (MFMA-fragment order): packed uint index j decomposes as
//   u = j&3, lane = (j>>2)&63, kk = (j>>8)&7, g = j>>11
//   n = g*16 + (lane&15), kc = kk*4 + (lane>>4), pc = kc*4 + u
// wpk1 logical row n = [W1l row n | W1r row n]; wpk2 row n = [W2l ; W2r]

__global__ void __launch_bounds__(512)
k_binprep(const int* __restrict__ ei, int E, int nb,
          int* __restrict__ cursor, unsigned* __restrict__ staged,
          const float* __restrict__ x, unsigned* __restrict__ xb, int nPairsX,
          const float* __restrict__ W1l, const float* __restrict__ W1r,
          const float* __restrict__ W2l, const float* __restrict__ W2r,
          unsigned* __restrict__ wpk1, unsigned* __restrict__ wpk2) {
  __shared__ int lh[512];
  __shared__ int lcur[NBMAX];
  int blk = blockIdx.x, tid = threadIdx.x;

  if (blk >= NBIN) {
    if (blk < NBIN + NCAST) {           // x -> bf16 pairs
      for (int i = (blk - NBIN) * 512 + tid; i < nPairsX; i += NCAST * 512) {
        float2 v = reinterpret_cast<const float2*>(x)[i];
        xb[i] = pack2(v.x, v.y);
      }
    } else {                            // weight packing (65536 pairs, fragment order)
      for (int i = (blk - NBIN - NCAST) * 512 + tid; i < 65536; i += NWPK * 512) {
        int j = i & 32767;
        int u = j & 3;
        int lane = (j >> 2) & 63;
        int kk = (j >> 8) & 7;
        int g = j >> 11;                 // 0..15
        int n = g * 16 + (lane & 15);
        int kc = kk * 4 + (lane >> 4);
        int pc = kc * 4 + u;             // pair col 0..127
        if (i < 32768) {                 // wpk1
          const float* s = (pc < 64) ? (W1l + (size_t)n * 128 + pc * 2)
                                     : (W1r + (size_t)n * 128 + (pc - 64) * 2);
          float2 v = *reinterpret_cast<const float2*>(s);
          wpk1[j] = pack2(v.x, v.y);
        } else {                         // wpk2
          const float* s = (n < 128) ? (W2l + (size_t)n * 256 + pc * 2)
                                     : (W2r + (size_t)(n - 128) * 256 + pc * 2);
          float2 v = *reinterpret_cast<const float2*>(s);
          wpk2[j] = pack2(v.x, v.y);
        }
      }
    }
    return;
  }

  // binning path: histogram -> reserve global runs -> direct scatter
  int e0 = blk * CHUNK;
  int e1 = min(e0 + CHUNK, E);
  lh[tid] = 0;
  __syncthreads();
  for (int e = e0 + tid; e < e1; e += 512)
    atomicAdd(&lh[((unsigned)ei[E + e]) >> 7], 1);
  __syncthreads();
  if (tid < nb)
    lcur[tid] = tid * CAP + atomicAdd(&cursor[tid], lh[tid]);
  __syncthreads();
  for (int e = e0 + tid; e < e1; e += 512) {
    int dst = ei[E + e];
    int src = ei[e];
    int b = ((unsigned)dst) >> 7;
    int pos = atomicAdd(&lcur[b], 1);
    staged[pos] = ((unsigned)src << 7) | (unsigned)(dst & 127);
  }
}

// ---------------- finalize: per-node (beg,end) + srcs (gapped) ----------------

__global__ void __launch_bounds__(512)
k_csr(const unsigned* __restrict__ staged, const int* __restrict__ cursor,
      int2* __restrict__ offs2, int* __restrict__ srcs, int N) {
  __shared__ int cnt[128];
  __shared__ int cur[128];
  int b = blockIdx.x;
  int tid = threadIdx.x;                  // 512
  int gbeg = b * CAP, gend = gbeg + cursor[b];
  if (tid < 128) cnt[tid] = 0;
  __syncthreads();
  for (int j = gbeg + tid; j < gend; j += 512)
    atomicAdd(&cnt[staged[j] & 127], 1);
  __syncthreads();
  if (tid < 64) {
    int v0 = cnt[tid * 2], v1 = cnt[tid * 2 + 1];
    int s = v0 + v1;
#pragma unroll
    for (int off = 1; off < 64; off <<= 1) {
      int t = __shfl_up(s, off, 64);
      if (tid >= off) s += t;
    }
    int exclp = s - (v0 + v1);
    int node = b * 128 + tid * 2;
    int beg0 = gbeg + exclp;
    int beg1 = beg0 + v0;
    cur[tid * 2]     = beg0;
    cur[tid * 2 + 1] = beg1;
    if (node < N)     offs2[node]     = make_int2(beg0, beg1);
    if (node + 1 < N) offs2[node + 1] = make_int2(beg1, beg1 + v1);
  }
  __syncthreads();
  for (int j = gbeg + tid; j < gend; j += 512) {
    unsigned v = staged[j];
    int pos = atomicAdd(&cur[v & 127], 1);
    srcs[pos] = (int)(v >> 7);
  }
}

// ---------------- mean aggregation: wave per node, reg-hoisted srcs ----------------

static __device__ __forceinline__ void acc8(float* s, uint4 p) {
  s[0] += lo2f(p.x); s[1] += hi2f(p.x);
  s[2] += lo2f(p.y); s[3] += hi2f(p.y);
  s[4] += lo2f(p.z); s[5] += hi2f(p.z);
  s[6] += lo2f(p.w); s[7] += hi2f(p.w);
}

// gather-sum of rows srcs[beg..end) of Z4 into s[8] (per 16-lane group layout)
static __device__ __forceinline__ void gather_sum(
    const uint4* __restrict__ Z4, const int* __restrict__ srcs,
    int beg, int end, int lane, int g, int c, float* s) {
  int deg = end - beg;
  if (deg <= 64) {
    // one coalesced load of the whole neighbor list; indices via shuffle.
    // ALL __shfl calls sit in wave-uniform control flow (deg is uniform):
    // ds_bpermute from an inactive source lane returns 0 on CDNA, so the
    // shuffle must never be under a divergent guard (r25 bug).
    int sidx = (lane < deg) ? srcs[beg + lane] : 0;
    int off = 0;
    for (; off + 16 <= deg; off += 16) {
      int i0 = __shfl(sidx, off +      g, 64);
      int i1 = __shfl(sidx, off +  4 + g, 64);
      int i2 = __shfl(sidx, off +  8 + g, 64);
      int i3 = __shfl(sidx, off + 12 + g, 64);
      uint4 p0 = Z4[(size_t)i0 * 16 + c];
      uint4 p1 = Z4[(size_t)i1 * 16 + c];
      uint4 p2 = Z4[(size_t)i2 * 16 + c];
      uint4 p3 = Z4[(size_t)i3 * 16 + c];
      acc8(s, p0); acc8(s, p1); acc8(s, p2); acc8(s, p3);
    }
    for (; off + 4 <= deg; off += 4) {
      int i0 = __shfl(sidx, off + g, 64);
      acc8(s, Z4[(size_t)i0 * 16 + c]);
    }
    // tail: shuffle hoisted OUT of the divergent guard; only the
    // accumulate is predicated.
    int srcl = off + g;
    int iT = __shfl(sidx, srcl < 64 ? srcl : 63, 64);
    if (srcl < deg)
      acc8(s, Z4[(size_t)iT * 16 + c]);
  } else {
    // fallback (deg > 64): original dependent-load path
    int j = beg;
    for (; j + 16 <= end; j += 16) {
      uint4 p0 = Z4[(size_t)srcs[j +      g] * 16 + c];
      uint4 p1 = Z4[(size_t)srcs[j +  4 + g] * 16 + c];
      uint4 p2 = Z4[(size_t)srcs[j +  8 + g] * 16 + c];
      uint4 p3 = Z4[(size_t)srcs[j + 12 + g] * 16 + c];
      acc8(s, p0); acc8(s, p1); acc8(s, p2); acc8(s, p3);
    }
    for (; j + 4 <= end; j += 4)
      acc8(s, Z4[(size_t)srcs[j + g] * 16 + c]);
    if (j + g < end)
      acc8(s, Z4[(size_t)srcs[j + g] * 16 + c]);
  }
}

__global__ void k_agg_store(const uint4* __restrict__ Z4,
                            const int2* __restrict__ offs2, const int* __restrict__ srcs,
                            uint4* __restrict__ out4, int N) {
  int node = blockIdx.x * 4 + (threadIdx.x >> 6);
  if (node >= N) return;
  int lane = threadIdx.x & 63;
  int g = lane >> 4, c = lane & 15;
  int2 be = offs2[node];
  int beg = be.x, end = be.y;
  float s[8] = {};
  gather_sum(Z4, srcs, beg, end, lane, g, c, s);
#pragma unroll
  for (int i = 0; i < 8; ++i) {
    s[i] += __shfl_xor(s[i], 16);
    s[i] += __shfl_xor(s[i], 32);
  }
  if (g == 0) {
    int d = end - beg;
    float inv = 1.0f / (float)(d > 0 ? d : 1);
    uint4 o;
    o.x = pack2(s[0] * inv, s[1] * inv);
    o.y = pack2(s[2] * inv, s[3] * inv);
    o.z = pack2(s[4] * inv, s[5] * inv);
    o.w = pack2(s[6] * inv, s[7] * inv);
    out4[(size_t)node * 16 + c] = o;
  }
}

// out = baseb + mean-gather(z); writes d_out (f32) once, no RMW
__global__ void k_agg_addout(const uint4* __restrict__ Z4,
                             const int2* __restrict__ offs2, const int* __restrict__ srcs,
                             const uint4* __restrict__ Bb4,
                             float* __restrict__ Out, int N) {
  int node = blockIdx.x * 4 + (threadIdx.x >> 6);
  if (node >= N) return;
  int lane = threadIdx.x & 63;
  int g = lane >> 4, c = lane & 15;
  int2 be = offs2[node];
  int beg = be.x, end = be.y;
  float s[8] = {};
  gather_sum(Z4, srcs, beg, end, lane, g, c, s);
#pragma unroll
  for (int i = 0; i < 8; ++i) {
    s[i] += __shfl_xor(s[i], 16);
    s[i] += __shfl_xor(s[i], 32);
  }
  if (g == 0) {
    int d = end - beg;
    float inv = 1.0f / (float)(d > 0 ? d : 1);
    uint4 bp = Bb4[(size_t)node * 16 + c];
    float4 o0, o1;
    o0.x = lo2f(bp.x) + s[0] * inv; o0.y = hi2f(bp.x) + s[1] * inv;
    o0.z = lo2f(bp.y) + s[2] * inv; o0.w = hi2f(bp.y) + s[3] * inv;
    o1.x = lo2f(bp.z) + s[4] * inv; o1.y = hi2f(bp.z) + s[5] * inv;
    o1.z = lo2f(bp.w) + s[6] * inv; o1.w = hi2f(bp.w) + s[7] * inv;
    float* op = Out + (size_t)node * 128 + c * 8;
    *reinterpret_cast<float4*>(op) = o0;
    *reinterpret_cast<float4*>(op + 4) = o1;
  }
}

// ---------------- fused dual-layer GEMM (single reused accumulator) ----------------
// Tile: rows mBase..mBase+63, all 256 cols. One 32KB LDS buffer At:
//   phase A: staged [agg1|xb] (XOR-swizzled), GEMM1 vs wpk1 -> acc
//   phase B: h = relu(acc+b1) written back into At (bf16, same swizzle)
//   phase C: acc re-zeroed, GEMM2 vs wpk2 -> zb (waves 0,1) / baseb (waves 2,3)
// A-swizzle: 16B chunk d of row r lives at pos p = (d&16)|((d^r)&15).
// B loads: fragment-order packed (k_binprep), contiguous 1KB per wave-load.

static __device__ __forceinline__ void stage_dual(
    const unsigned short* A1, const unsigned short* A2, int mBase,
    unsigned short* At /* LDS 64x256 */) {
  int t = threadIdx.x;
#pragma unroll
  for (int it = 0; it < 8; ++it) {
    int q = it * 256 + t;
    int r = q >> 5;
    int p = q & 31;
    int d = (p & 16) | ((p ^ r) & 15);
    const unsigned short* g = (d < 16)
        ? (A1 + (size_t)(mBase + r) * 128 + d * 8)
        : (A2 + (size_t)(mBase + r) * 128 + (d - 16) * 8);
    __builtin_amdgcn_global_load_lds(
        (const __attribute__((address_space(1))) unsigned*)g,
        (__attribute__((address_space(3))) unsigned*)&At[q * 8], 16, 0, 0);
  }
}

__global__ void __launch_bounds__(256, 3)
k_gemm12(const unsigned short* __restrict__ A1, const unsigned short* __restrict__ A2,
         const unsigned short* __restrict__ Wpk1, const float* __restrict__ b1,
         const unsigned short* __restrict__ Wpk2, const float* __restrict__ b2,
         unsigned short* __restrict__ Zb, unsigned short* __restrict__ Bb, int M) {
  __shared__ unsigned short At[64 * 256];
  int mBase = blockIdx.x * 64;
  stage_dual(A1, A2, mBase, At);
  int lane = threadIdx.x & 63, wave = threadIdx.x >> 6;
  int l15 = lane & 15, quad = lane >> 4;
  const short8* Wf1 = reinterpret_cast<const short8*>(Wpk1);
  const short8* Wf2 = reinterpret_cast<const short8*>(Wpk2);

  // ---- GEMM1: [agg|x] @ wpk1^T ----
  floatx4 acc[4][4] = {};
  __syncthreads();
#pragma unroll 2
  for (int kk = 0; kk < 8; ++kk) {
    short8 b[4];
#pragma unroll
    for (int t = 0; t < 4; ++t)
      b[t] = Wf1[((wave * 4 + t) * 8 + kk) * 64 + lane];
    int kc = kk * 4 + quad;
#pragma unroll
    for (int s = 0; s < 4; ++s) {
      int row = s * 16 + l15;
      int pos = (kc & 16) | ((kc ^ row) & 15);
      short8 a = *reinterpret_cast<const short8*>(&At[row * 256 + pos * 8]);
#pragma unroll
      for (int t = 0; t < 4; ++t)
        acc[s][t] = __builtin_amdgcn_mfma_f32_16x16x32_bf16(a, b[t], acc[s][t], 0, 0, 0);
    }
  }
  __syncthreads();   // all GEMM1 reads of At complete

  // ---- write h = relu(acc + b1) into At (bf16, A-layout swizzle); kill acc ----
#pragma unroll
  for (int t = 0; t < 4; ++t) {
    int n = wave * 64 + t * 16 + l15;
    float bv = b1[n];
    int d = n >> 3, nl = n & 7;
#pragma unroll
    for (int s = 0; s < 4; ++s) {
#pragma unroll
      for (int r = 0; r < 4; ++r) {
        int m = s * 16 + quad * 4 + r;
        int pos = (d & 16) | ((d ^ m) & 15);
        At[m * 256 + pos * 8 + nl] = f2b(fmaxf(acc[s][t][r] + bv, 0.f));
      }
    }
  }
  // re-zero the SAME accumulator (ends acc's GEMM1 live range)
#pragma unroll
  for (int s = 0; s < 4; ++s)
#pragma unroll
    for (int t = 0; t < 4; ++t)
      acc[s][t] = floatx4{0.f, 0.f, 0.f, 0.f};
  __syncthreads();   // h tile visible to all waves

  // ---- GEMM2: h @ wpk2^T (same acc registers) ----
#pragma unroll 2
  for (int kk = 0; kk < 8; ++kk) {
    short8 b[4];
#pragma unroll
    for (int t = 0; t < 4; ++t)
      b[t] = Wf2[((wave * 4 + t) * 8 + kk) * 64 + lane];
    int kc = kk * 4 + quad;
#pragma unroll
    for (int s = 0; s < 4; ++s) {
      int row = s * 16 + l15;
      int pos = (kc & 16) | ((kc ^ row) & 15);
      short8 a = *reinterpret_cast<const short8*>(&At[row * 256 + pos * 8]);
#pragma unroll
      for (int t = 0; t < 4; ++t)
        acc[s][t] = __builtin_amdgcn_mfma_f32_16x16x32_bf16(a, b[t], acc[s][t], 0, 0, 0);
    }
  }
  if (wave < 2) {        // z path, cols 0..127, bf16, no bias
#pragma unroll
    for (int t = 0; t < 4; ++t) {
      int n = wave * 64 + t * 16 + l15;
#pragma unroll
      for (int s = 0; s < 4; ++s)
#pragma unroll
        for (int r = 0; r < 4; ++r) {
          int m = mBase + s * 16 + quad * 4 + r;
          if (m < M) Zb[(size_t)m * 128 + n] = f2b(acc[s][t][r]);
        }
    }
  } else {               // base path, cols 0..127, bf16 + bias
#pragma unroll
    for (int t = 0; t < 4; ++t) {
      int n = (wave - 2) * 64 + t * 16 + l15;
      float bv = b2[n];
#pragma unroll
      for (int s = 0; s < 4; ++s)
#pragma unroll
        for (int r = 0; r < 4; ++r) {
          int m = mBase + s * 16 + quad * 4 + r;
          if (m < M) Bb[(size_t)m * 128 + n] = f2b(acc[s][t][r] + bv);
        }
    }
  }
}

// ---------------- launch ----------------

extern "C" void kernel_launch(void* const* d_in, const int* in_sizes, int n_in,
                              void* d_out, int out_size, void* d_ws, size_t ws_size,
                              hipStream_t stream) {
  const float* x   = (const float*)d_in[0];
  const int*   ei  = (const int*)d_in[1];
  const float* W1l = (const float*)d_in[2];
  const float* b1  = (const float*)d_in[3];
  const float* W1r = (const float*)d_in[4];
  const float* W2l = (const float*)d_in[5];
  const float* b2  = (const float*)d_in[6];
  const float* W2r = (const float*)d_in[7];
  float* out = (float*)d_out;

  int N = in_sizes[0] / IN_C;   // 50000
  int E = in_sizes[1] / 2;      // 800000
  int nb = (N + 127) >> 7;      // 391

  char* p = (char*)d_ws;
  auto alloc = [&](size_t bytes) -> void* {
    void* r = (void*)p;
    p += (bytes + 255) & ~(size_t)255;
    return r;
  };
  int* cursor  = (int*)alloc((size_t)(nb + 1) * 4);
  unsigned* staged = (unsigned*)alloc((size_t)nb * CAP * 4);
  int2* offs2 = (int2*)alloc((size_t)N * 8);
  int* srcs   = (int*)alloc((size_t)nb * CAP * 4);
  unsigned* xb   = (unsigned*)alloc((size_t)N * IN_C * 2);   // N x 64 uints
  unsigned* agg1 = (unsigned*)alloc((size_t)N * IN_C * 2);
  unsigned short* zb = (unsigned short*)alloc((size_t)N * OUT_C * 2);
  unsigned short* baseb = (unsigned short*)alloc((size_t)N * OUT_C * 2);
  unsigned* wpk1 = (unsigned*)alloc((size_t)HID_C * 256 * 2);  // 32768 uints
  unsigned* wpk2 = (unsigned*)alloc((size_t)256 * HID_C * 2);  // 32768 uints
  (void)alloc(64 * 512);   // tail pad for last-block over-reads

  // cursor zero (counts are CAP-relative), fused binning+prep, finalize
  hipMemsetAsync(cursor, 0, (size_t)(nb + 1) * 4, stream);
  k_binprep<<<NBIN + NCAST + NWPK, 512, 0, stream>>>(
      ei, E, nb, cursor, staged, x, xb, N * IN_C / 2,
      W1l, W1r, W2l, W2r, wpk1, wpk2);
  k_csr<<<nb, 512, 0, stream>>>(staged, cursor, offs2, srcs, N);

  int mBlocks = (N + 63) / 64;

  // layer-1 gather, then fused dual GEMM (h never hits global)
  k_agg_store<<<(N + 3) / 4, 256, 0, stream>>>(
      (const uint4*)xb, offs2, srcs, (uint4*)agg1, N);
  k_gemm12<<<mBlocks, 256, 0, stream>>>(
      (const unsigned short*)agg1, (const unsigned short*)xb,
      (const unsigned short*)wpk1, b1,
      (const unsigned short*)wpk2, b2, zb, baseb, N);

  // out = baseb + mean-gather(z)
  k_agg_addout<<<(N + 3) / 4, 256, 0, stream>>>(
      (const uint4*)zb, offs2, srcs, (const uint4*)baseb, out, N);
}

// Round 15
// 194.329 us; speedup vs baseline: 1.1379x; 1.0011x over previous
//
#include <hip/hip_runtime.h>
#include <hip/hip_bf16.h>

// GraphSAGE 2-layer encoder, MI355X. Round 27.
// - Anchor (r26, 194.5us): r15 fragment-order weights, r18 bucket binprep,
//   r19 4-wave gemm12, r24 csr@512, r26 shfl-gather (wave-uniform shuffles
//   only - CDNA ds_bpermute reads 0 from inactive source lanes).
// - SINGLE LEVER (same mechanism as r26's win, applied to the two scatter
//   kernels): register-stage the re-read values so scatter passes are
//   load-free.
//   * k_binprep binning: dst+src staged into 12 regs BEFORE the histogram
//     (latency hides under LDS atomics; binning runs at only ~8 waves/CU so
//     the old pass-2 dependent loads were exposed).
//   * k_csr: stage up to 5 staged[] values/thread unconditionally (bucket
//     region is CAP-sized and in-bounds; USE stays guarded), issued before
//     the cnt zero/barrier.
//   All unroll indices compile-time (no scratch). Summation order unchanged.
// 5 kernels + 1.6KB memset.

typedef short short8 __attribute__((ext_vector_type(8)));
typedef float floatx4 __attribute__((ext_vector_type(4)));

#define IN_C  128
#define HID_C 256
#define OUT_C 128
#define NBMAX 400      // buckets of 128 nodes: ceil(50000/128)=391
#define CHUNK 3072     // edges per binning block (= 6 * 512)
#define CAP   2560     // per-bucket slot capacity (= 5 * 512)
#define NBIN  261      // binning blocks: 261*3072 >= 800000
#define NCAST 200      // x-cast blocks
#define NWPK  56       // weight-pack blocks

static __device__ __forceinline__ unsigned short f2b(float f) {
  union { float f; unsigned u; } v; v.f = f;
  unsigned r = v.u + 0x7fffu + ((v.u >> 16) & 1u);   // RNE
  return (unsigned short)(r >> 16);
}
static __device__ __forceinline__ unsigned pack2(float a, float b) {
  return (unsigned)f2b(a) | ((unsigned)f2b(b) << 16);
}
static __device__ __forceinline__ float lo2f(unsigned u) {
  union { unsigned u; float f; } v; v.u = u << 16; return v.f;
}
static __device__ __forceinline__ float hi2f(unsigned u) {
  union { unsigned u; float f; } v; v.u = u & 0xffff0000u; return v.f;
}

// ---------------- binprep: binning + x cast + weight pack (one launch) ----------------
// staged value = (src<<7) | (dst&127); bucket b's run: [b*CAP, b*CAP+cursor[b])
// Weight pack (MFMA-fragment order): packed uint index j decomposes as
//   u = j&3, lane = (j>>2)&63, kk = (j>>8)&7, g = j>>11
//   n = g*16 + (lane&15), kc = kk*4 + (lane>>4), pc = kc*4 + u
// wpk1 logical row n = [W1l row n | W1r row n]; wpk2 row n = [W2l ; W2r]

__global__ void __launch_bounds__(512)
k_binprep(const int* __restrict__ ei, int E, int nb,
          int* __restrict__ cursor, unsigned* __restrict__ staged,
          const float* __restrict__ x, unsigned* __restrict__ xb, int nPairsX,
          const float* __restrict__ W1l, const float* __restrict__ W1r,
          const float* __restrict__ W2l, const float* __restrict__ W2r,
          unsigned* __restrict__ wpk1, unsigned* __restrict__ wpk2) {
  __shared__ int lh[512];
  __shared__ int lcur[NBMAX];
  int blk = blockIdx.x, tid = threadIdx.x;

  if (blk >= NBIN) {
    if (blk < NBIN + NCAST) {           // x -> bf16 pairs
      for (int i = (blk - NBIN) * 512 + tid; i < nPairsX; i += NCAST * 512) {
        float2 v = reinterpret_cast<const float2*>(x)[i];
        xb[i] = pack2(v.x, v.y);
      }
    } else {                            // weight packing (65536 pairs, fragment order)
      for (int i = (blk - NBIN - NCAST) * 512 + tid; i < 65536; i += NWPK * 512) {
        int j = i & 32767;
        int u = j & 3;
        int lane = (j >> 2) & 63;
        int kk = (j >> 8) & 7;
        int g = j >> 11;                 // 0..15
        int n = g * 16 + (lane & 15);
        int kc = kk * 4 + (lane >> 4);
        int pc = kc * 4 + u;             // pair col 0..127
        if (i < 32768) {                 // wpk1
          const float* s = (pc < 64) ? (W1l + (size_t)n * 128 + pc * 2)
                                     : (W1r + (size_t)n * 128 + (pc - 64) * 2);
          float2 v = *reinterpret_cast<const float2*>(s);
          wpk1[j] = pack2(v.x, v.y);
        } else {                         // wpk2
          const float* s = (n < 128) ? (W2l + (size_t)n * 256 + pc * 2)
                                     : (W2r + (size_t)(n - 128) * 256 + pc * 2);
          float2 v = *reinterpret_cast<const float2*>(s);
          wpk2[j] = pack2(v.x, v.y);
        }
      }
    }
    return;
  }

  // binning path: stage edges to regs -> histogram -> reserve -> scatter
  int e0 = blk * CHUNK;
  int e1 = min(e0 + CHUNK, E);
  int dstv[6], srcv[6];
#pragma unroll
  for (int it = 0; it < 6; ++it) {       // issued before histogram: latency
    int e = e0 + it * 512 + tid;         // hides under the LDS-atomic phase
    if (e < e1) { dstv[it] = ei[E + e]; srcv[it] = ei[e]; }
  }
  lh[tid] = 0;
  __syncthreads();
#pragma unroll
  for (int it = 0; it < 6; ++it) {
    int e = e0 + it * 512 + tid;
    if (e < e1) atomicAdd(&lh[((unsigned)dstv[it]) >> 7], 1);
  }
  __syncthreads();
  if (tid < nb)
    lcur[tid] = tid * CAP + atomicAdd(&cursor[tid], lh[tid]);
  __syncthreads();
#pragma unroll
  for (int it = 0; it < 6; ++it) {       // scatter pass: load-free
    int e = e0 + it * 512 + tid;
    if (e < e1) {
      int b = ((unsigned)dstv[it]) >> 7;
      int pos = atomicAdd(&lcur[b], 1);
      staged[pos] = ((unsigned)srcv[it] << 7) | (unsigned)(dstv[it] & 127);
    }
  }
}

// ---------------- finalize: per-node (beg,end) + srcs (gapped) ----------------

__global__ void __launch_bounds__(512)
k_csr(const unsigned* __restrict__ staged, const int* __restrict__ cursor,
      int2* __restrict__ offs2, int* __restrict__ srcs, int N) {
  __shared__ int cnt[128];
  __shared__ int cur[128];
  int b = blockIdx.x;
  int tid = threadIdx.x;                  // 512
  int gbeg = b * CAP, gend = gbeg + cursor[b];
  unsigned sv[5];
#pragma unroll
  for (int it = 0; it < 5; ++it)          // unconditional: bucket region is
    sv[it] = staged[gbeg + it * 512 + tid]; // CAP-sized, always in-bounds
  if (tid < 128) cnt[tid] = 0;
  __syncthreads();
#pragma unroll
  for (int it = 0; it < 5; ++it) {
    int j = gbeg + it * 512 + tid;
    if (j < gend) atomicAdd(&cnt[sv[it] & 127], 1);
  }
  __syncthreads();
  if (tid < 64) {
    int v0 = cnt[tid * 2], v1 = cnt[tid * 2 + 1];
    int s = v0 + v1;
#pragma unroll
    for (int off = 1; off < 64; off <<= 1) {
      int t = __shfl_up(s, off, 64);
      if (tid >= off) s += t;
    }
    int exclp = s - (v0 + v1);
    int node = b * 128 + tid * 2;
    int beg0 = gbeg + exclp;
    int beg1 = beg0 + v0;
    cur[tid * 2]     = beg0;
    cur[tid * 2 + 1] = beg1;
    if (node < N)     offs2[node]     = make_int2(beg0, beg1);
    if (node + 1 < N) offs2[node + 1] = make_int2(beg1, beg1 + v1);
  }
  __syncthreads();
#pragma unroll
  for (int it = 0; it < 5; ++it) {        // scatter pass: load-free
    int j = gbeg + it * 512 + tid;
    if (j < gend) {
      unsigned v = sv[it];
      int pos = atomicAdd(&cur[v & 127], 1);
      srcs[pos] = (int)(v >> 7);
    }
  }
}

// ---------------- mean aggregation: wave per node, reg-hoisted srcs ----------------

static __device__ __forceinline__ void acc8(float* s, uint4 p) {
  s[0] += lo2f(p.x); s[1] += hi2f(p.x);
  s[2] += lo2f(p.y); s[3] += hi2f(p.y);
  s[4] += lo2f(p.z); s[5] += hi2f(p.z);
  s[6] += lo2f(p.w); s[7] += hi2f(p.w);
}

// gather-sum of rows srcs[beg..end) of Z4 into s[8] (per 16-lane group layout)
static __device__ __forceinline__ void gather_sum(
    const uint4* __restrict__ Z4, const int* __restrict__ srcs,
    int beg, int end, int lane, int g, int c, float* s) {
  int deg = end - beg;
  if (deg <= 64) {
    // one coalesced load of the whole neighbor list; indices via shuffle.
    // ALL __shfl calls sit in wave-uniform control flow (deg is uniform):
    // ds_bpermute from an inactive source lane returns 0 on CDNA, so the
    // shuffle must never be under a divergent guard (r25 bug).
    int sidx = (lane < deg) ? srcs[beg + lane] : 0;
    int off = 0;
    for (; off + 16 <= deg; off += 16) {
      int i0 = __shfl(sidx, off +      g, 64);
      int i1 = __shfl(sidx, off +  4 + g, 64);
      int i2 = __shfl(sidx, off +  8 + g, 64);
      int i3 = __shfl(sidx, off + 12 + g, 64);
      uint4 p0 = Z4[(size_t)i0 * 16 + c];
      uint4 p1 = Z4[(size_t)i1 * 16 + c];
      uint4 p2 = Z4[(size_t)i2 * 16 + c];
      uint4 p3 = Z4[(size_t)i3 * 16 + c];
      acc8(s, p0); acc8(s, p1); acc8(s, p2); acc8(s, p3);
    }
    for (; off + 4 <= deg; off += 4) {
      int i0 = __shfl(sidx, off + g, 64);
      acc8(s, Z4[(size_t)i0 * 16 + c]);
    }
    // tail: shuffle hoisted OUT of the divergent guard; only the
    // accumulate is predicated.
    int srcl = off + g;
    int iT = __shfl(sidx, srcl < 64 ? srcl : 63, 64);
    if (srcl < deg)
      acc8(s, Z4[(size_t)iT * 16 + c]);
  } else {
    // fallback (deg > 64): original dependent-load path
    int j = beg;
    for (; j + 16 <= end; j += 16) {
      uint4 p0 = Z4[(size_t)srcs[j +      g] * 16 + c];
      uint4 p1 = Z4[(size_t)srcs[j +  4 + g] * 16 + c];
      uint4 p2 = Z4[(size_t)srcs[j +  8 + g] * 16 + c];
      uint4 p3 = Z4[(size_t)srcs[j + 12 + g] * 16 + c];
      acc8(s, p0); acc8(s, p1); acc8(s, p2); acc8(s, p3);
    }
    for (; j + 4 <= end; j += 4)
      acc8(s, Z4[(size_t)srcs[j + g] * 16 + c]);
    if (j + g < end)
      acc8(s, Z4[(size_t)srcs[j + g] * 16 + c]);
  }
}

__global__ void k_agg_store(const uint4* __restrict__ Z4,
                            const int2* __restrict__ offs2, const int* __restrict__ srcs,
                            uint4* __restrict__ out4, int N) {
  int node = blockIdx.x * 4 + (threadIdx.x >> 6);
  if (node >= N) return;
  int lane = threadIdx.x & 63;
  int g = lane >> 4, c = lane & 15;
  int2 be = offs2[node];
  int beg = be.x, end = be.y;
  float s[8] = {};
  gather_sum(Z4, srcs, beg, end, lane, g, c, s);
#pragma unroll
  for (int i = 0; i < 8; ++i) {
    s[i] += __shfl_xor(s[i], 16);
    s[i] += __shfl_xor(s[i], 32);
  }
  if (g == 0) {
    int d = end - beg;
    float inv = 1.0f / (float)(d > 0 ? d : 1);
    uint4 o;
    o.x = pack2(s[0] * inv, s[1] * inv);
    o.y = pack2(s[2] * inv, s[3] * inv);
    o.z = pack2(s[4] * inv, s[5] * inv);
    o.w = pack2(s[6] * inv, s[7] * inv);
    out4[(size_t)node * 16 + c] = o;
  }
}

// out = baseb + mean-gather(z); writes d_out (f32) once, no RMW
__global__ void k_agg_addout(const uint4* __restrict__ Z4,
                             const int2* __restrict__ offs2, const int* __restrict__ srcs,
                             const uint4* __restrict__ Bb4,
                             float* __restrict__ Out, int N) {
  int node = blockIdx.x * 4 + (threadIdx.x >> 6);
  if (node >= N) return;
  int lane = threadIdx.x & 63;
  int g = lane >> 4, c = lane & 15;
  int2 be = offs2[node];
  int beg = be.x, end = be.y;
  float s[8] = {};
  gather_sum(Z4, srcs, beg, end, lane, g, c, s);
#pragma unroll
  for (int i = 0; i < 8; ++i) {
    s[i] += __shfl_xor(s[i], 16);
    s[i] += __shfl_xor(s[i], 32);
  }
  if (g == 0) {
    int d = end - beg;
    float inv = 1.0f / (float)(d > 0 ? d : 1);
    uint4 bp = Bb4[(size_t)node * 16 + c];
    float4 o0, o1;
    o0.x = lo2f(bp.x) + s[0] * inv; o0.y = hi2f(bp.x) + s[1] * inv;
    o0.z = lo2f(bp.y) + s[2] * inv; o0.w = hi2f(bp.y) + s[3] * inv;
    o1.x = lo2f(bp.z) + s[4] * inv; o1.y = hi2f(bp.z) + s[5] * inv;
    o1.z = lo2f(bp.w) + s[6] * inv; o1.w = hi2f(bp.w) + s[7] * inv;
    float* op = Out + (size_t)node * 128 + c * 8;
    *reinterpret_cast<float4*>(op) = o0;
    *reinterpret_cast<float4*>(op + 4) = o1;
  }
}

// ---------------- fused dual-layer GEMM (single reused accumulator) ----------------
// Tile: rows mBase..mBase+63, all 256 cols. One 32KB LDS buffer At:
//   phase A: staged [agg1|xb] (XOR-swizzled), GEMM1 vs wpk1 -> acc
//   phase B: h = relu(acc+b1) written back into At (bf16, same swizzle)
//   phase C: acc re-zeroed, GEMM2 vs wpk2 -> zb (waves 0,1) / baseb (waves 2,3)
// A-swizzle: 16B chunk d of row r lives at pos p = (d&16)|((d^r)&15).
// B loads: fragment-order packed (k_binprep), contiguous 1KB per wave-load.

static __device__ __forceinline__ void stage_dual(
    const unsigned short* A1, const unsigned short* A2, int mBase,
    unsigned short* At /* LDS 64x256 */) {
  int t = threadIdx.x;
#pragma unroll
  for (int it = 0; it < 8; ++it) {
    int q = it * 256 + t;
    int r = q >> 5;
    int p = q & 31;
    int d = (p & 16) | ((p ^ r) & 15);
    const unsigned short* g = (d < 16)
        ? (A1 + (size_t)(mBase + r) * 128 + d * 8)
        : (A2 + (size_t)(mBase + r) * 128 + (d - 16) * 8);
    __builtin_amdgcn_global_load_lds(
        (const __attribute__((address_space(1))) unsigned*)g,
        (__attribute__((address_space(3))) unsigned*)&At[q * 8], 16, 0, 0);
  }
}

__global__ void __launch_bounds__(256, 3)
k_gemm12(const unsigned short* __restrict__ A1, const unsigned short* __restrict__ A2,
         const unsigned short* __restrict__ Wpk1, const float* __restrict__ b1,
         const unsigned short* __restrict__ Wpk2, const float* __restrict__ b2,
         unsigned short* __restrict__ Zb, unsigned short* __restrict__ Bb, int M) {
  __shared__ unsigned short At[64 * 256];
  int mBase = blockIdx.x * 64;
  stage_dual(A1, A2, mBase, At);
  int lane = threadIdx.x & 63, wave = threadIdx.x >> 6;
  int l15 = lane & 15, quad = lane >> 4;
  const short8* Wf1 = reinterpret_cast<const short8*>(Wpk1);
  const short8* Wf2 = reinterpret_cast<const short8*>(Wpk2);

  // ---- GEMM1: [agg|x] @ wpk1^T ----
  floatx4 acc[4][4] = {};
  __syncthreads();
#pragma unroll 2
  for (int kk = 0; kk < 8; ++kk) {
    short8 b[4];
#pragma unroll
    for (int t = 0; t < 4; ++t)
      b[t] = Wf1[((wave * 4 + t) * 8 + kk) * 64 + lane];
    int kc = kk * 4 + quad;
#pragma unroll
    for (int s = 0; s < 4; ++s) {
      int row = s * 16 + l15;
      int pos = (kc & 16) | ((kc ^ row) & 15);
      short8 a = *reinterpret_cast<const short8*>(&At[row * 256 + pos * 8]);
#pragma unroll
      for (int t = 0; t < 4; ++t)
        acc[s][t] = __builtin_amdgcn_mfma_f32_16x16x32_bf16(a, b[t], acc[s][t], 0, 0, 0);
    }
  }
  __syncthreads();   // all GEMM1 reads of At complete

  // ---- write h = relu(acc + b1) into At (bf16, A-layout swizzle); kill acc ----
#pragma unroll
  for (int t = 0; t < 4; ++t) {
    int n = wave * 64 + t * 16 + l15;
    float bv = b1[n];
    int d = n >> 3, nl = n & 7;
#pragma unroll
    for (int s = 0; s < 4; ++s) {
#pragma unroll
      for (int r = 0; r < 4; ++r) {
        int m = s * 16 + quad * 4 + r;
        int pos = (d & 16) | ((d ^ m) & 15);
        At[m * 256 + pos * 8 + nl] = f2b(fmaxf(acc[s][t][r] + bv, 0.f));
      }
    }
  }
  // re-zero the SAME accumulator (ends acc's GEMM1 live range)
#pragma unroll
  for (int s = 0; s < 4; ++s)
#pragma unroll
    for (int t = 0; t < 4; ++t)
      acc[s][t] = floatx4{0.f, 0.f, 0.f, 0.f};
  __syncthreads();   // h tile visible to all waves

  // ---- GEMM2: h @ wpk2^T (same acc registers) ----
#pragma unroll 2
  for (int kk = 0; kk < 8; ++kk) {
    short8 b[4];
#pragma unroll
    for (int t = 0; t < 4; ++t)
      b[t] = Wf2[((wave * 4 + t) * 8 + kk) * 64 + lane];
    int kc = kk * 4 + quad;
#pragma unroll
    for (int s = 0; s < 4; ++s) {
      int row = s * 16 + l15;
      int pos = (kc & 16) | ((kc ^ row) & 15);
      short8 a = *reinterpret_cast<const short8*>(&At[row * 256 + pos * 8]);
#pragma unroll
      for (int t = 0; t < 4; ++t)
        acc[s][t] = __builtin_amdgcn_mfma_f32_16x16x32_bf16(a, b[t], acc[s][t], 0, 0, 0);
    }
  }
  if (wave < 2) {        // z path, cols 0..127, bf16, no bias
#pragma unroll
    for (int t = 0; t < 4; ++t) {
      int n = wave * 64 + t * 16 + l15;
#pragma unroll
      for (int s = 0; s < 4; ++s)
#pragma unroll
        for (int r = 0; r < 4; ++r) {
          int m = mBase + s * 16 + quad * 4 + r;
          if (m < M) Zb[(size_t)m * 128 + n] = f2b(acc[s][t][r]);
        }
    }
  } else {               // base path, cols 0..127, bf16 + bias
#pragma unroll
    for (int t = 0; t < 4; ++t) {
      int n = (wave - 2) * 64 + t * 16 + l15;
      float bv = b2[n];
#pragma unroll
      for (int s = 0; s < 4; ++s)
#pragma unroll
        for (int r = 0; r < 4; ++r) {
          int m = mBase + s * 16 + quad * 4 + r;
          if (m < M) Bb[(size_t)m * 128 + n] = f2b(acc[s][t][r] + bv);
        }
    }
  }
}

// ---------------- launch ----------------

extern "C" void kernel_launch(void* const* d_in, const int* in_sizes, int n_in,
                              void* d_out, int out_size, void* d_ws, size_t ws_size,
                              hipStream_t stream) {
  const float* x   = (const float*)d_in[0];
  const int*   ei  = (const int*)d_in[1];
  const float* W1l = (const float*)d_in[2];
  const float* b1  = (const float*)d_in[3];
  const float* W1r = (const float*)d_in[4];
  const float* W2l = (const float*)d_in[5];
  const float* b2  = (const float*)d_in[6];
  const float* W2r = (const float*)d_in[7];
  float* out = (float*)d_out;

  int N = in_sizes[0] / IN_C;   // 50000
  int E = in_sizes[1] / 2;      // 800000
  int nb = (N + 127) >> 7;      // 391

  char* p = (char*)d_ws;
  auto alloc = [&](size_t bytes) -> void* {
    void* r = (void*)p;
    p += (bytes + 255) & ~(size_t)255;
    return r;
  };
  int* cursor  = (int*)alloc((size_t)(nb + 1) * 4);
  unsigned* staged = (unsigned*)alloc((size_t)nb * CAP * 4);
  int2* offs2 = (int2*)alloc((size_t)N * 8);
  int* srcs   = (int*)alloc((size_t)nb * CAP * 4);
  unsigned* xb   = (unsigned*)alloc((size_t)N * IN_C * 2);   // N x 64 uints
  unsigned* agg1 = (unsigned*)alloc((size_t)N * IN_C * 2);
  unsigned short* zb = (unsigned short*)alloc((size_t)N * OUT_C * 2);
  unsigned short* baseb = (unsigned short*)alloc((size_t)N * OUT_C * 2);
  unsigned* wpk1 = (unsigned*)alloc((size_t)HID_C * 256 * 2);  // 32768 uints
  unsigned* wpk2 = (unsigned*)alloc((size_t)256 * HID_C * 2);  // 32768 uints
  (void)alloc(64 * 512);   // tail pad for last-block over-reads

  // cursor zero (counts are CAP-relative), fused binning+prep, finalize
  hipMemsetAsync(cursor, 0, (size_t)(nb + 1) * 4, stream);
  k_binprep<<<NBIN + NCAST + NWPK, 512, 0, stream>>>(
      ei, E, nb, cursor, staged, x, xb, N * IN_C / 2,
      W1l, W1r, W2l, W2r, wpk1, wpk2);
  k_csr<<<nb, 512, 0, stream>>>(staged, cursor, offs2, srcs, N);

  int mBlocks = (N + 63) / 64;

  // layer-1 gather, then fused dual GEMM (h never hits global)
  k_agg_store<<<(N + 3) / 4, 256, 0, stream>>>(
      (const uint4*)xb, offs2, srcs, (uint4*)agg1, N);
  k_gemm12<<<mBlocks, 256, 0, stream>>>(
      (const unsigned short*)agg1, (const unsigned short*)xb,
      (const unsigned short*)wpk1, b1,
      (const unsigned short*)wpk2, b2, zb, baseb, N);

  // out = baseb + mean-gather(z)
  k_agg_addout<<<(N + 3) / 4, 256, 0, stream>>>(
      (const uint4*)zb, offs2, srcs, (const uint4*)baseb, out, N);
}